// Round 3
// baseline (1353.925 us; speedup 1.0000x reference)
//
#include <hip/hip_runtime.h>

#define N_NODES  100000
#define N_EDGES  3200000
#define N_GRAPHS 1000
#define HDIM     64

// ---------------- bf16 <-> f32 helpers (storage-only precision) ----------------

__device__ inline float ldh(const float* p) { return *p; }
__device__ inline float ldh(const unsigned short* p) {
    unsigned int u = ((unsigned int)*p) << 16;
    float f; __builtin_memcpy(&f, &u, 4); return f;
}
__device__ inline void sth(float* p, float v) { *p = v; }
__device__ inline void sth(unsigned short* p, float v) {
    unsigned int b; __builtin_memcpy(&b, &v, 4);
    unsigned int r = (b + 0x7FFFu + ((b >> 16) & 1u)) >> 16;   // RNE
    *p = (unsigned short)r;
}

__device__ inline int clampi(int v, int lo, int hi) {
    return v < lo ? lo : (v > hi ? hi : v);
}

// ---------------- utility ----------------

__global__ void k_zero(int* __restrict__ p, int n) {
    int i = blockIdx.x * blockDim.x + threadIdx.x;
    if (i < n) p[i] = 0;
}

// ---------------- CSR construction (edge_index is int32 on device) ----------------

__global__ void k_count(const int* __restrict__ ei, int* __restrict__ deg) {
    int e = blockIdx.x * blockDim.x + threadIdx.x;
    if (e < N_EDGES) {
        int d = clampi(ei[N_EDGES + e], 0, N_NODES - 1);   // dst
        atomicAdd(&deg[d], 1);
    }
}

__global__ void k_scan(const int* __restrict__ deg, int* __restrict__ off) {
    const int T = 1024;
    const int chunk = (N_NODES + T - 1) / T;   // 98
    __shared__ int sums[T];
    __shared__ int pref[T];
    int t = threadIdx.x;
    int base = t * chunk;
    int s = 0;
    for (int i = 0; i < chunk; ++i) {
        int idx = base + i;
        if (idx < N_NODES) s += deg[idx];
    }
    sums[t] = s;
    __syncthreads();
    if (t == 0) {
        int run = 0;
        for (int i = 0; i < T; ++i) { pref[i] = run; run += sums[i]; }
    }
    __syncthreads();
    int run = pref[t];
    for (int i = 0; i < chunk; ++i) {
        int idx = base + i;
        if (idx < N_NODES) { off[idx] = run; run += deg[idx]; }
    }
    if (t == T - 1) off[N_NODES] = pref[T - 1] + sums[T - 1];
}

__global__ void k_copy_int(const int* __restrict__ a, int* __restrict__ b, int n) {
    int i = blockIdx.x * blockDim.x + threadIdx.x;
    if (i < n) b[i] = a[i];
}

__global__ void k_fill(const int* __restrict__ ei, int* __restrict__ cur,
                       int* __restrict__ adj) {
    int e = blockIdx.x * blockDim.x + threadIdx.x;
    if (e < N_EDGES) {
        int s = clampi(ei[e], 0, N_NODES - 1);
        int d = clampi(ei[N_EDGES + e], 0, N_NODES - 1);
        int p = atomicAdd(&cur[d], 1);
        if (p >= 0 && p < N_EDGES) adj[p] = s;
    }
}

// ---------------- Layer 1 (F_IN = 3) ----------------

template <typename T>
__global__ __launch_bounds__(256) void k_layer1(
        const float* __restrict__ x, const int* __restrict__ off,
        const int* __restrict__ adj, const float* __restrict__ epsp,
        const float* __restrict__ W1, const float* __restrict__ b1,
        T* __restrict__ hout) {
    int wid  = (blockIdx.x * blockDim.x + threadIdx.x) >> 6;   // node
    int lane = threadIdx.x & 63;
    if (wid >= N_NODES) return;
    int o0 = off[wid], o1 = off[wid + 1];
    float a0 = 0.f, a1 = 0.f, a2 = 0.f;
    for (int e = o0 + lane; e < o1; e += 64) {
        int s = adj[e];
        a0 += x[s * 3 + 0];
        a1 += x[s * 3 + 1];
        a2 += x[s * 3 + 2];
    }
    #pragma unroll
    for (int d = 32; d; d >>= 1) {
        a0 += __shfl_xor(a0, d);
        a1 += __shfl_xor(a1, d);
        a2 += __shfl_xor(a2, d);
    }
    float ep = 1.0f + epsp[0];
    float s0 = ep * x[wid * 3 + 0] + a0;
    float s1 = ep * x[wid * 3 + 1] + a1;
    float s2 = ep * x[wid * 3 + 2] + a2;
    float o = b1[lane] + s0 * W1[lane] + s1 * W1[64 + lane] + s2 * W1[128 + lane];
    sth(&hout[(size_t)wid * 64 + lane], fmaxf(o, 0.f));
}

// ---------------- Layers 2 & 3 (64 -> 64), fused agg + matmul ----------------

template <typename T>
__global__ __launch_bounds__(256) void k_layer(
        const T* __restrict__ hin, const int* __restrict__ off,
        const int* __restrict__ adj, const float* __restrict__ epsp,
        const float* __restrict__ W, const float* __restrict__ b,
        T* __restrict__ hout) {
    __shared__ float Wl[64 * 64];
    __shared__ float bl[64];
    for (int i = threadIdx.x; i < 64 * 64; i += 256) Wl[i] = W[i];
    if (threadIdx.x < 64) bl[threadIdx.x] = b[threadIdx.x];
    __syncthreads();

    int wid  = (blockIdx.x * blockDim.x + threadIdx.x) >> 6;   // node
    int lane = threadIdx.x & 63;
    if (wid >= N_NODES) return;

    float ep = 1.0f + epsp[0];
    float v = ep * ldh(&hin[(size_t)wid * 64 + lane]);
    int o0 = off[wid], o1 = off[wid + 1];
    for (int e = o0; e < o1; ++e) {
        int s = adj[e];                           // wave-uniform
        v += ldh(&hin[(size_t)s * 64 + lane]);    // coalesced per edge
    }

    float acc = bl[lane];
    #pragma unroll
    for (int k = 0; k < 64; ++k) {
        acc += __shfl(v, k) * Wl[k * 64 + lane];
    }
    sth(&hout[(size_t)wid * 64 + lane], fmaxf(acc, 0.f));
}

// ---------------- Pooling (batch is int32 on device) ----------------

template <typename T>
__global__ __launch_bounds__(256) void k_pool(
        const T* __restrict__ h, const int* __restrict__ batch,
        float* __restrict__ pooled, int* __restrict__ cnt) {
    int wid  = (blockIdx.x * blockDim.x + threadIdx.x) >> 6;
    int lane = threadIdx.x & 63;
    if (wid >= N_NODES) return;
    int g = clampi(batch[wid], 0, N_GRAPHS - 1);
    atomicAdd(&pooled[g * 64 + lane], ldh(&h[(size_t)wid * 64 + lane]));
    if (lane == 0) atomicAdd(&cnt[g], 1);
}

// ---------------- Head: mean, 64->10 relu, 10->1 ----------------

__global__ __launch_bounds__(256) void k_head(
        const float* __restrict__ pooled, const int* __restrict__ cnt,
        const float* __restrict__ Wf1, const float* __restrict__ bf1,
        const float* __restrict__ Wf2, const float* __restrict__ bf2,
        float* __restrict__ out) {
    int g = blockIdx.x * blockDim.x + threadIdx.x;
    if (g >= N_GRAPHS) return;
    float inv = 1.0f / fmaxf((float)cnt[g], 1.0f);
    float p[64];
    #pragma unroll
    for (int k = 0; k < 64; ++k) p[k] = pooled[g * 64 + k] * inv;
    float o = bf2[0];
    #pragma unroll
    for (int j = 0; j < 10; ++j) {
        float s = bf1[j];
        #pragma unroll
        for (int k = 0; k < 64; ++k) s += p[k] * Wf1[k * 10 + j];
        o += fmaxf(s, 0.f) * Wf2[j];
    }
    out[g] = o;
}

// ---------------- launch ----------------

extern "C" void kernel_launch(void* const* d_in, const int* in_sizes, int n_in,
                              void* d_out, int out_size, void* d_ws, size_t ws_size,
                              hipStream_t stream) {
    const float* x     = (const float*)d_in[0];
    const int*   ei    = (const int*)d_in[1];    // int64 in ref -> int32 on device
    const int*   batch = (const int*)d_in[2];    // int64 in ref -> int32 on device
    const float* eps1 = (const float*)d_in[3];
    const float* eps2 = (const float*)d_in[4];
    const float* eps3 = (const float*)d_in[5];
    const float* W1 = (const float*)d_in[6];
    const float* b1 = (const float*)d_in[7];
    const float* W2 = (const float*)d_in[8];
    const float* b2 = (const float*)d_in[9];
    const float* W3 = (const float*)d_in[10];
    const float* b3 = (const float*)d_in[11];
    const float* Wf1 = (const float*)d_in[12];
    const float* bf1 = (const float*)d_in[13];
    const float* Wf2 = (const float*)d_in[14];
    const float* bf2 = (const float*)d_in[15];
    float* out = (float*)d_out;

    const size_t H64 = (size_t)N_NODES * HDIM;          // 6,400,000 elems
    // fixed tail: pooled(64000 f32) cnt(1000) deg(100000) off(100004) adj(3200000)
    const size_t tail_bytes = (64000ull + 1000 + 100000 + 100004 + 3200000) * 4;
    const bool use32 = ws_size >= 2 * H64 * 4 + tail_bytes + 4096;

    char* base = (char*)d_ws;
    size_t hbytes = H64 * (use32 ? 4 : 2);
    void* hA = (void*)base;
    void* hB = (void*)(base + hbytes);
    char* q = base + 2 * hbytes;
    float* pooled = (float*)q;            q += 64000ull * 4;
    int*   cnt    = (int*)q;              q += 1000ull * 4;
    int*   deg    = (int*)q;              q += 100000ull * 4;
    int*   off    = (int*)q;              q += 100004ull * 4;
    int*   adj    = (int*)q;

    const int TB = 256;
    // zero deg and pooled+cnt (contiguous 65,000 words)
    k_zero<<<(N_NODES + TB - 1) / TB, TB, 0, stream>>>(deg, N_NODES);
    k_zero<<<(65000 + TB - 1) / TB, TB, 0, stream>>>((int*)pooled, 65000);

    // CSR build
    k_count<<<(N_EDGES + TB - 1) / TB, TB, 0, stream>>>(ei, deg);
    k_scan<<<1, 1024, 0, stream>>>(deg, off);
    k_copy_int<<<(N_NODES + TB - 1) / TB, TB, 0, stream>>>(off, deg, N_NODES);
    k_fill<<<(N_EDGES + TB - 1) / TB, TB, 0, stream>>>(ei, deg, adj);

    const int NODE_BLOCKS = (int)((H64 + TB - 1) / TB);   // 4 nodes (waves) per block

    if (use32) {
        float* A = (float*)hA; float* B = (float*)hB;
        k_layer1<float><<<NODE_BLOCKS, TB, 0, stream>>>(x, off, adj, eps1, W1, b1, A);
        k_layer<float><<<NODE_BLOCKS, TB, 0, stream>>>(A, off, adj, eps2, W2, b2, B);
        k_layer<float><<<NODE_BLOCKS, TB, 0, stream>>>(B, off, adj, eps3, W3, b3, A);
        k_pool<float><<<NODE_BLOCKS, TB, 0, stream>>>(A, batch, pooled, cnt);
    } else {
        unsigned short* A = (unsigned short*)hA;
        unsigned short* B = (unsigned short*)hB;
        k_layer1<unsigned short><<<NODE_BLOCKS, TB, 0, stream>>>(x, off, adj, eps1, W1, b1, A);
        k_layer<unsigned short><<<NODE_BLOCKS, TB, 0, stream>>>(A, off, adj, eps2, W2, b2, B);
        k_layer<unsigned short><<<NODE_BLOCKS, TB, 0, stream>>>(B, off, adj, eps3, W3, b3, A);
        k_pool<unsigned short><<<NODE_BLOCKS, TB, 0, stream>>>(A, batch, pooled, cnt);
    }

    k_head<<<(N_GRAPHS + TB - 1) / TB, TB, 0, stream>>>(pooled, cnt, Wf1, bf1, Wf2, bf2, out);
}

// Round 4
// 1022.818 us; speedup vs baseline: 1.3237x; 1.3237x over previous
//
#include <hip/hip_runtime.h>

#define N_NODES  100000
#define N_EDGES  3200000
#define N_GRAPHS 1000
#define HDIM     64

// ---------------- bf16 <-> f32 helpers (storage-only precision) ----------------

__device__ inline float ldh(const float* p) { return *p; }
__device__ inline float ldh(const unsigned short* p) {
    unsigned int u = ((unsigned int)*p) << 16;
    float f; __builtin_memcpy(&f, &u, 4); return f;
}
__device__ inline void sth(float* p, float v) { *p = v; }
__device__ inline void sth(unsigned short* p, float v) {
    unsigned int b; __builtin_memcpy(&b, &v, 4);
    unsigned int r = (b + 0x7FFFu + ((b >> 16) & 1u)) >> 16;   // RNE
    *p = (unsigned short)r;
}

__device__ inline int clampi(int v, int lo, int hi) {
    return v < lo ? lo : (v > hi ? hi : v);
}

// ---------------- utility ----------------

__global__ void k_zero(int* __restrict__ p, int n) {
    int i = blockIdx.x * blockDim.x + threadIdx.x;
    if (i < n) p[i] = 0;
}

// ---------------- CSR construction (edge_index is int32 on device) ----------------

__global__ void k_count(const int* __restrict__ ei, int* __restrict__ deg) {
    int e = blockIdx.x * blockDim.x + threadIdx.x;
    if (e < N_EDGES) {
        int d = clampi(ei[N_EDGES + e], 0, N_NODES - 1);   // dst
        atomicAdd(&deg[d], 1);
    }
}

__global__ void k_scan(const int* __restrict__ deg, int* __restrict__ off) {
    const int T = 1024;
    const int chunk = (N_NODES + T - 1) / T;   // 98
    __shared__ int sums[T];
    __shared__ int pref[T];
    int t = threadIdx.x;
    int base = t * chunk;
    int s = 0;
    for (int i = 0; i < chunk; ++i) {
        int idx = base + i;
        if (idx < N_NODES) s += deg[idx];
    }
    sums[t] = s;
    __syncthreads();
    if (t == 0) {
        int run = 0;
        for (int i = 0; i < T; ++i) { pref[i] = run; run += sums[i]; }
    }
    __syncthreads();
    int run = pref[t];
    for (int i = 0; i < chunk; ++i) {
        int idx = base + i;
        if (idx < N_NODES) { off[idx] = run; run += deg[idx]; }
    }
    if (t == T - 1) off[N_NODES] = pref[T - 1] + sums[T - 1];
}

__global__ void k_copy_int(const int* __restrict__ a, int* __restrict__ b, int n) {
    int i = blockIdx.x * blockDim.x + threadIdx.x;
    if (i < n) b[i] = a[i];
}

__global__ void k_fill(const int* __restrict__ ei, int* __restrict__ cur,
                       int* __restrict__ adj) {
    int e = blockIdx.x * blockDim.x + threadIdx.x;
    if (e < N_EDGES) {
        int s = clampi(ei[e], 0, N_NODES - 1);
        int d = clampi(ei[N_EDGES + e], 0, N_NODES - 1);
        int p = atomicAdd(&cur[d], 1);
        if (p >= 0 && p < N_EDGES) adj[p] = s;
    }
}

// ---------------- Layer 1 (F_IN = 3) ----------------

template <typename T>
__global__ __launch_bounds__(256) void k_layer1(
        const float* __restrict__ x, const int* __restrict__ off,
        const int* __restrict__ adj, const float* __restrict__ epsp,
        const float* __restrict__ W1, const float* __restrict__ b1,
        T* __restrict__ hout) {
    int wid  = (blockIdx.x * blockDim.x + threadIdx.x) >> 6;   // node
    int lane = threadIdx.x & 63;
    if (wid >= N_NODES) return;
    int o0 = off[wid], o1 = off[wid + 1];
    float a0 = 0.f, a1 = 0.f, a2 = 0.f;
    for (int e = o0 + lane; e < o1; e += 64) {
        int s = adj[e];
        a0 += x[s * 3 + 0];
        a1 += x[s * 3 + 1];
        a2 += x[s * 3 + 2];
    }
    #pragma unroll
    for (int d = 32; d; d >>= 1) {
        a0 += __shfl_xor(a0, d);
        a1 += __shfl_xor(a1, d);
        a2 += __shfl_xor(a2, d);
    }
    float ep = 1.0f + epsp[0];
    float s0 = ep * x[wid * 3 + 0] + a0;
    float s1 = ep * x[wid * 3 + 1] + a1;
    float s2 = ep * x[wid * 3 + 2] + a2;
    float o = b1[lane] + s0 * W1[lane] + s1 * W1[64 + lane] + s2 * W1[128 + lane];
    sth(&hout[(size_t)wid * 64 + lane], fmaxf(o, 0.f));
}

// ---------------- fused aggregation + 64x64 matmul, one wave per node ----------------
// Returns relu(b + ((1+eps)*h_self + sum_nbr h_nbr) @ W) for this lane's column.

template <typename T>
__device__ inline float node_forward(
        const T* __restrict__ hin, const int* __restrict__ off,
        const int* __restrict__ adj, float ep,
        const float* __restrict__ Wl, const float* __restrict__ bl,
        int wid, int lane) {
    float v = ep * ldh(&hin[(size_t)wid * 64 + lane]);
    int o0 = off[wid], o1 = off[wid + 1];
    for (int base = o0; base < o1; base += 64) {
        int n = o1 - base; n = n < 64 ? n : 64;
        int li = lane < n ? lane : n - 1;
        int idx = adj[base + li];            // one coalesced read per 64 edges
        int n8 = n & ~7;
        float a0 = 0.f, a1 = 0.f, a2 = 0.f, a3 = 0.f;
        float a4 = 0.f, a5 = 0.f, a6 = 0.f, a7 = 0.f;
        for (int k = 0; k < n8; k += 8) {    // 8 independent gathers in flight
            int s0 = __shfl(idx, k + 0), s1 = __shfl(idx, k + 1);
            int s2 = __shfl(idx, k + 2), s3 = __shfl(idx, k + 3);
            int s4 = __shfl(idx, k + 4), s5 = __shfl(idx, k + 5);
            int s6 = __shfl(idx, k + 6), s7 = __shfl(idx, k + 7);
            a0 += ldh(&hin[(size_t)s0 * 64 + lane]);
            a1 += ldh(&hin[(size_t)s1 * 64 + lane]);
            a2 += ldh(&hin[(size_t)s2 * 64 + lane]);
            a3 += ldh(&hin[(size_t)s3 * 64 + lane]);
            a4 += ldh(&hin[(size_t)s4 * 64 + lane]);
            a5 += ldh(&hin[(size_t)s5 * 64 + lane]);
            a6 += ldh(&hin[(size_t)s6 * 64 + lane]);
            a7 += ldh(&hin[(size_t)s7 * 64 + lane]);
        }
        for (int k = n8; k < n; ++k) {
            int s = __shfl(idx, k);
            a0 += ldh(&hin[(size_t)s * 64 + lane]);
        }
        v += ((a0 + a1) + (a2 + a3)) + ((a4 + a5) + (a6 + a7));
    }
    float acc = bl[lane];
    #pragma unroll
    for (int k = 0; k < 64; ++k) {
        acc += __shfl(v, k) * Wl[k * 64 + lane];
    }
    return fmaxf(acc, 0.f);
}

template <typename T>
__global__ __launch_bounds__(1024) void k_layer(
        const T* __restrict__ hin, const int* __restrict__ off,
        const int* __restrict__ adj, const float* __restrict__ epsp,
        const float* __restrict__ W, const float* __restrict__ b,
        T* __restrict__ hout) {
    __shared__ float Wl[64 * 64];
    __shared__ float bl[64];
    for (int i = threadIdx.x; i < 64 * 64; i += 1024) Wl[i] = W[i];
    if (threadIdx.x < 64) bl[threadIdx.x] = b[threadIdx.x];
    __syncthreads();
    int wid  = (blockIdx.x * blockDim.x + threadIdx.x) >> 6;
    int lane = threadIdx.x & 63;
    if (wid >= N_NODES) return;
    float r = node_forward(hin, off, adj, 1.0f + epsp[0], Wl, bl, wid, lane);
    sth(&hout[(size_t)wid * 64 + lane], r);
}

// layer 3 variant: pool directly, skip the feature store
template <typename T>
__global__ __launch_bounds__(1024) void k_layer_pool(
        const T* __restrict__ hin, const int* __restrict__ off,
        const int* __restrict__ adj, const float* __restrict__ epsp,
        const float* __restrict__ W, const float* __restrict__ b,
        const int* __restrict__ batch,
        float* __restrict__ pooled, int* __restrict__ cnt) {
    __shared__ float Wl[64 * 64];
    __shared__ float bl[64];
    for (int i = threadIdx.x; i < 64 * 64; i += 1024) Wl[i] = W[i];
    if (threadIdx.x < 64) bl[threadIdx.x] = b[threadIdx.x];
    __syncthreads();
    int wid  = (blockIdx.x * blockDim.x + threadIdx.x) >> 6;
    int lane = threadIdx.x & 63;
    if (wid >= N_NODES) return;
    float r = node_forward(hin, off, adj, 1.0f + epsp[0], Wl, bl, wid, lane);
    int g = clampi(batch[wid], 0, N_GRAPHS - 1);
    atomicAdd(&pooled[g * 64 + lane], r);
    if (lane == 0) atomicAdd(&cnt[g], 1);
}

// ---------------- Head: mean, 64->10 relu, 10->1 ----------------

__global__ __launch_bounds__(256) void k_head(
        const float* __restrict__ pooled, const int* __restrict__ cnt,
        const float* __restrict__ Wf1, const float* __restrict__ bf1,
        const float* __restrict__ Wf2, const float* __restrict__ bf2,
        float* __restrict__ out) {
    int g = blockIdx.x * blockDim.x + threadIdx.x;
    if (g >= N_GRAPHS) return;
    float inv = 1.0f / fmaxf((float)cnt[g], 1.0f);
    float p[64];
    #pragma unroll
    for (int k = 0; k < 64; ++k) p[k] = pooled[g * 64 + k] * inv;
    float o = bf2[0];
    #pragma unroll
    for (int j = 0; j < 10; ++j) {
        float s = bf1[j];
        #pragma unroll
        for (int k = 0; k < 64; ++k) s += p[k] * Wf1[k * 10 + j];
        o += fmaxf(s, 0.f) * Wf2[j];
    }
    out[g] = o;
}

// ---------------- launch ----------------

extern "C" void kernel_launch(void* const* d_in, const int* in_sizes, int n_in,
                              void* d_out, int out_size, void* d_ws, size_t ws_size,
                              hipStream_t stream) {
    const float* x     = (const float*)d_in[0];
    const int*   ei    = (const int*)d_in[1];    // int64 in ref -> int32 on device
    const int*   batch = (const int*)d_in[2];
    const float* eps1 = (const float*)d_in[3];
    const float* eps2 = (const float*)d_in[4];
    const float* eps3 = (const float*)d_in[5];
    const float* W1 = (const float*)d_in[6];
    const float* b1 = (const float*)d_in[7];
    const float* W2 = (const float*)d_in[8];
    const float* b2 = (const float*)d_in[9];
    const float* W3 = (const float*)d_in[10];
    const float* b3 = (const float*)d_in[11];
    const float* Wf1 = (const float*)d_in[12];
    const float* bf1 = (const float*)d_in[13];
    const float* Wf2 = (const float*)d_in[14];
    const float* bf2 = (const float*)d_in[15];
    float* out = (float*)d_out;

    const size_t H64 = (size_t)N_NODES * HDIM;          // 6,400,000 elems
    const size_t tail_bytes = (64000ull + 1000 + 100000 + 100004 + 3200000) * 4;
    const bool use32 = ws_size >= 2 * H64 * 4 + tail_bytes + 4096;

    char* base = (char*)d_ws;
    size_t hbytes = H64 * (use32 ? 4 : 2);
    void* hA = (void*)base;
    void* hB = (void*)(base + hbytes);
    char* q = base + 2 * hbytes;
    float* pooled = (float*)q;            q += 64000ull * 4;
    int*   cnt    = (int*)q;              q += 1000ull * 4;
    int*   deg    = (int*)q;              q += 100000ull * 4;
    int*   off    = (int*)q;              q += 100004ull * 4;
    int*   adj    = (int*)q;

    const int TB = 256;
    k_zero<<<(N_NODES + TB - 1) / TB, TB, 0, stream>>>(deg, N_NODES);
    k_zero<<<(65000 + TB - 1) / TB, TB, 0, stream>>>((int*)pooled, 65000);

    // CSR build
    k_count<<<(N_EDGES + TB - 1) / TB, TB, 0, stream>>>(ei, deg);
    k_scan<<<1, 1024, 0, stream>>>(deg, off);
    k_copy_int<<<(N_NODES + TB - 1) / TB, TB, 0, stream>>>(off, deg, N_NODES);
    k_fill<<<(N_EDGES + TB - 1) / TB, TB, 0, stream>>>(ei, deg, adj);

    const int L1_BLOCKS = (int)((H64 + TB - 1) / TB);        // 4 nodes/block @256
    const int LBLOCKS   = (N_NODES + 15) / 16;               // 16 nodes/block @1024

    if (use32) {
        float* A = (float*)hA; float* B = (float*)hB;
        k_layer1<float><<<L1_BLOCKS, TB, 0, stream>>>(x, off, adj, eps1, W1, b1, A);
        k_layer<float><<<LBLOCKS, 1024, 0, stream>>>(A, off, adj, eps2, W2, b2, B);
        k_layer_pool<float><<<LBLOCKS, 1024, 0, stream>>>(B, off, adj, eps3, W3, b3,
                                                          batch, pooled, cnt);
    } else {
        unsigned short* A = (unsigned short*)hA;
        unsigned short* B = (unsigned short*)hB;
        k_layer1<unsigned short><<<L1_BLOCKS, TB, 0, stream>>>(x, off, adj, eps1, W1, b1, A);
        k_layer<unsigned short><<<LBLOCKS, 1024, 0, stream>>>(A, off, adj, eps2, W2, b2, B);
        k_layer_pool<unsigned short><<<LBLOCKS, 1024, 0, stream>>>(B, off, adj, eps3, W3, b3,
                                                                   batch, pooled, cnt);
    }

    k_head<<<(N_GRAPHS + TB - 1) / TB, TB, 0, stream>>>(pooled, cnt, Wf1, bf1, Wf2, bf2, out);
}

// Round 5
// 907.531 us; speedup vs baseline: 1.4919x; 1.1270x over previous
//
#include <hip/hip_runtime.h>

#define N_NODES  100000
#define N_EDGES  3200000
#define N_GRAPHS 1000
#define HDIM     64

#define LOG_WIN  14                       // dst window = 16384 nodes
#define NPASS    ((N_NODES + (1 << LOG_WIN) - 1) >> LOG_WIN)   // 7

// ---------------- bf16 (storage) <-> f32 (math) ----------------

__device__ inline float ldh(const unsigned short* p) {
    unsigned int u = ((unsigned int)*p) << 16;
    float f; __builtin_memcpy(&f, &u, 4); return f;
}
__device__ inline void sth(unsigned short* p, float v) {
    unsigned int b; __builtin_memcpy(&b, &v, 4);
    unsigned int r = (b + 0x7FFFu + ((b >> 16) & 1u)) >> 16;   // RNE
    *p = (unsigned short)r;
}

__device__ inline int clampi(int v, int lo, int hi) {
    return v < lo ? lo : (v > hi ? hi : v);
}

// ---------------- utility ----------------

__global__ void k_zero(int* __restrict__ p, int n) {
    int i = blockIdx.x * blockDim.x + threadIdx.x;
    if (i < n) p[i] = 0;
}

// ---------------- CSR construction, dst-windowed passes ----------------

__global__ void k_count(const int* __restrict__ ei, int* __restrict__ deg) {
    int e = blockIdx.x * blockDim.x + threadIdx.x;
    int p = blockIdx.y;
    if (e < N_EDGES) {
        int d = clampi(ei[N_EDGES + e], 0, N_NODES - 1);
        if ((d >> LOG_WIN) == p) atomicAdd(&deg[d], 1);
    }
}

__global__ void k_scan(const int* __restrict__ deg, int* __restrict__ off) {
    const int T = 1024;
    const int chunk = (N_NODES + T - 1) / T;   // 98
    __shared__ int sums[T];
    __shared__ int pref[T];
    int t = threadIdx.x;
    int base = t * chunk;
    int s = 0;
    for (int i = 0; i < chunk; ++i) {
        int idx = base + i;
        if (idx < N_NODES) s += deg[idx];
    }
    sums[t] = s;
    __syncthreads();
    if (t == 0) {
        int run = 0;
        for (int i = 0; i < T; ++i) { pref[i] = run; run += sums[i]; }
    }
    __syncthreads();
    int run = pref[t];
    for (int i = 0; i < chunk; ++i) {
        int idx = base + i;
        if (idx < N_NODES) { off[idx] = run; run += deg[idx]; }
    }
    if (t == T - 1) off[N_NODES] = pref[T - 1] + sums[T - 1];
}

__global__ void k_copy_int(const int* __restrict__ a, int* __restrict__ b, int n) {
    int i = blockIdx.x * blockDim.x + threadIdx.x;
    if (i < n) b[i] = a[i];
}

__global__ void k_fill(const int* __restrict__ ei, int* __restrict__ cur,
                       int* __restrict__ adj) {
    int e = blockIdx.x * blockDim.x + threadIdx.x;
    int p = blockIdx.y;
    if (e < N_EDGES) {
        int d = clampi(ei[N_EDGES + e], 0, N_NODES - 1);
        if ((d >> LOG_WIN) == p) {
            int s = clampi(ei[e], 0, N_NODES - 1);
            int q = atomicAdd(&cur[d], 1);
            if (q >= 0 && q < N_EDGES) adj[q] = s;
        }
    }
}

// ---------------- Layer 1 (F_IN = 3) ----------------

__global__ __launch_bounds__(256) void k_layer1(
        const float* __restrict__ x, const int* __restrict__ off,
        const int* __restrict__ adj, const float* __restrict__ epsp,
        const float* __restrict__ W1, const float* __restrict__ b1,
        unsigned short* __restrict__ hout) {
    int wid  = (blockIdx.x * blockDim.x + threadIdx.x) >> 6;   // node
    int lane = threadIdx.x & 63;
    if (wid >= N_NODES) return;
    int o0 = off[wid], o1 = off[wid + 1];
    float a0 = 0.f, a1 = 0.f, a2 = 0.f;
    for (int e = o0 + lane; e < o1; e += 64) {
        int s = adj[e];
        a0 += x[s * 3 + 0];
        a1 += x[s * 3 + 1];
        a2 += x[s * 3 + 2];
    }
    #pragma unroll
    for (int d = 32; d; d >>= 1) {
        a0 += __shfl_xor(a0, d);
        a1 += __shfl_xor(a1, d);
        a2 += __shfl_xor(a2, d);
    }
    float ep = 1.0f + epsp[0];
    float s0 = ep * x[wid * 3 + 0] + a0;
    float s1 = ep * x[wid * 3 + 1] + a1;
    float s2 = ep * x[wid * 3 + 2] + a2;
    float o = b1[lane] + s0 * W1[lane] + s1 * W1[64 + lane] + s2 * W1[128 + lane];
    sth(&hout[(size_t)wid * 64 + lane], fmaxf(o, 0.f));
}

// ---------------- fused aggregation + 64x64 matmul, one wave per node ----------------

__device__ inline float node_forward(
        const unsigned short* __restrict__ hin, const int* __restrict__ off,
        const int* __restrict__ adj, float ep,
        const float* __restrict__ Wl, const float* __restrict__ bl,
        int wid, int lane) {
    float v = ep * ldh(&hin[(size_t)wid * 64 + lane]);
    int o0 = off[wid], o1 = off[wid + 1];
    for (int base = o0; base < o1; base += 64) {
        int n = o1 - base; n = n < 64 ? n : 64;
        int li = lane < n ? lane : n - 1;
        int idx = adj[base + li];            // one coalesced read per 64 edges
        int n8 = n & ~7;
        float a0 = 0.f, a1 = 0.f, a2 = 0.f, a3 = 0.f;
        float a4 = 0.f, a5 = 0.f, a6 = 0.f, a7 = 0.f;
        for (int k = 0; k < n8; k += 8) {    // 8 independent gathers in flight
            int s0 = __shfl(idx, k + 0), s1 = __shfl(idx, k + 1);
            int s2 = __shfl(idx, k + 2), s3 = __shfl(idx, k + 3);
            int s4 = __shfl(idx, k + 4), s5 = __shfl(idx, k + 5);
            int s6 = __shfl(idx, k + 6), s7 = __shfl(idx, k + 7);
            a0 += ldh(&hin[(size_t)s0 * 64 + lane]);
            a1 += ldh(&hin[(size_t)s1 * 64 + lane]);
            a2 += ldh(&hin[(size_t)s2 * 64 + lane]);
            a3 += ldh(&hin[(size_t)s3 * 64 + lane]);
            a4 += ldh(&hin[(size_t)s4 * 64 + lane]);
            a5 += ldh(&hin[(size_t)s5 * 64 + lane]);
            a6 += ldh(&hin[(size_t)s6 * 64 + lane]);
            a7 += ldh(&hin[(size_t)s7 * 64 + lane]);
        }
        for (int k = n8; k < n; ++k) {
            int s = __shfl(idx, k);
            a0 += ldh(&hin[(size_t)s * 64 + lane]);
        }
        v += ((a0 + a1) + (a2 + a3)) + ((a4 + a5) + (a6 + a7));
    }
    float acc = bl[lane];
    #pragma unroll
    for (int k = 0; k < 64; ++k) {
        acc += __shfl(v, k) * Wl[k * 64 + lane];
    }
    return fmaxf(acc, 0.f);
}

__global__ __launch_bounds__(1024) void k_layer(
        const unsigned short* __restrict__ hin, const int* __restrict__ off,
        const int* __restrict__ adj, const float* __restrict__ epsp,
        const float* __restrict__ W, const float* __restrict__ b,
        unsigned short* __restrict__ hout) {
    __shared__ float Wl[64 * 64];
    __shared__ float bl[64];
    for (int i = threadIdx.x; i < 64 * 64; i += 1024) Wl[i] = W[i];
    if (threadIdx.x < 64) bl[threadIdx.x] = b[threadIdx.x];
    __syncthreads();
    int wid  = (blockIdx.x * blockDim.x + threadIdx.x) >> 6;
    int lane = threadIdx.x & 63;
    if (wid >= N_NODES) return;
    float r = node_forward(hin, off, adj, 1.0f + epsp[0], Wl, bl, wid, lane);
    sth(&hout[(size_t)wid * 64 + lane], r);
}

// layer 3 variant: pool directly, skip the feature store
__global__ __launch_bounds__(1024) void k_layer_pool(
        const unsigned short* __restrict__ hin, const int* __restrict__ off,
        const int* __restrict__ adj, const float* __restrict__ epsp,
        const float* __restrict__ W, const float* __restrict__ b,
        const int* __restrict__ batch,
        float* __restrict__ pooled, int* __restrict__ cnt) {
    __shared__ float Wl[64 * 64];
    __shared__ float bl[64];
    for (int i = threadIdx.x; i < 64 * 64; i += 1024) Wl[i] = W[i];
    if (threadIdx.x < 64) bl[threadIdx.x] = b[threadIdx.x];
    __syncthreads();
    int wid  = (blockIdx.x * blockDim.x + threadIdx.x) >> 6;
    int lane = threadIdx.x & 63;
    if (wid >= N_NODES) return;
    float r = node_forward(hin, off, adj, 1.0f + epsp[0], Wl, bl, wid, lane);
    int g = clampi(batch[wid], 0, N_GRAPHS - 1);
    atomicAdd(&pooled[g * 64 + lane], r);
    if (lane == 0) atomicAdd(&cnt[g], 1);
}

// ---------------- Head: mean, 64->10 relu, 10->1 ----------------

__global__ __launch_bounds__(256) void k_head(
        const float* __restrict__ pooled, const int* __restrict__ cnt,
        const float* __restrict__ Wf1, const float* __restrict__ bf1,
        const float* __restrict__ Wf2, const float* __restrict__ bf2,
        float* __restrict__ out) {
    int g = blockIdx.x * blockDim.x + threadIdx.x;
    if (g >= N_GRAPHS) return;
    float inv = 1.0f / fmaxf((float)cnt[g], 1.0f);
    float p[64];
    #pragma unroll
    for (int k = 0; k < 64; ++k) p[k] = pooled[g * 64 + k] * inv;
    float o = bf2[0];
    #pragma unroll
    for (int j = 0; j < 10; ++j) {
        float s = bf1[j];
        #pragma unroll
        for (int k = 0; k < 64; ++k) s += p[k] * Wf1[k * 10 + j];
        o += fmaxf(s, 0.f) * Wf2[j];
    }
    out[g] = o;
}

// ---------------- launch ----------------

extern "C" void kernel_launch(void* const* d_in, const int* in_sizes, int n_in,
                              void* d_out, int out_size, void* d_ws, size_t ws_size,
                              hipStream_t stream) {
    const float* x     = (const float*)d_in[0];
    const int*   ei    = (const int*)d_in[1];    // int64 in ref -> int32 on device
    const int*   batch = (const int*)d_in[2];
    const float* eps1 = (const float*)d_in[3];
    const float* eps2 = (const float*)d_in[4];
    const float* eps3 = (const float*)d_in[5];
    const float* W1 = (const float*)d_in[6];
    const float* b1 = (const float*)d_in[7];
    const float* W2 = (const float*)d_in[8];
    const float* b2 = (const float*)d_in[9];
    const float* W3 = (const float*)d_in[10];
    const float* b3 = (const float*)d_in[11];
    const float* Wf1 = (const float*)d_in[12];
    const float* bf1 = (const float*)d_in[13];
    const float* Wf2 = (const float*)d_in[14];
    const float* bf2 = (const float*)d_in[15];
    float* out = (float*)d_out;

    const size_t H64 = (size_t)N_NODES * HDIM;          // 6,400,000 elems

    char* base = (char*)d_ws;
    unsigned short* hA = (unsigned short*)base;                    // 12.8 MB
    unsigned short* hB = (unsigned short*)(base + H64 * 2);        // 12.8 MB
    char* q = base + 2 * H64 * 2;
    float* pooled = (float*)q;            q += 64000ull * 4;
    int*   cnt    = (int*)q;              q += 1000ull * 4;
    int*   deg    = (int*)q;              q += 100000ull * 4;
    int*   off    = (int*)q;              q += 100004ull * 4;
    int*   adj    = (int*)q;

    const int TB = 256;
    k_zero<<<(N_NODES + TB - 1) / TB, TB, 0, stream>>>(deg, N_NODES);
    k_zero<<<(65000 + TB - 1) / TB, TB, 0, stream>>>((int*)pooled, 65000);

    // CSR build, dst-windowed
    dim3 egrid((N_EDGES + TB - 1) / TB, NPASS);
    k_count<<<egrid, TB, 0, stream>>>(ei, deg);
    k_scan<<<1, 1024, 0, stream>>>(deg, off);
    k_copy_int<<<(N_NODES + TB - 1) / TB, TB, 0, stream>>>(off, deg, N_NODES);
    k_fill<<<egrid, TB, 0, stream>>>(ei, deg, adj);

    const int L1_BLOCKS = (int)((H64 + TB - 1) / TB);        // 4 nodes/block @256
    const int LBLOCKS   = (N_NODES + 15) / 16;               // 16 nodes/block @1024

    k_layer1<<<L1_BLOCKS, TB, 0, stream>>>(x, off, adj, eps1, W1, b1, hA);
    k_layer<<<LBLOCKS, 1024, 0, stream>>>(hA, off, adj, eps2, W2, b2, hB);
    k_layer_pool<<<LBLOCKS, 1024, 0, stream>>>(hB, off, adj, eps3, W3, b3,
                                               batch, pooled, cnt);

    k_head<<<(N_GRAPHS + TB - 1) / TB, TB, 0, stream>>>(pooled, cnt, Wf1, bf1, Wf2, bf2, out);
}

// Round 6
// 840.292 us; speedup vs baseline: 1.6113x; 1.0800x over previous
//
#include <hip/hip_runtime.h>

#define N_NODES  100000
#define N_EDGES  3200000
#define N_GRAPHS 1000
#define HDIM     64

#define LOG_WIN  14                       // dst window for k_fill = 16384 nodes
#define NPASS    ((N_NODES + (1 << LOG_WIN) - 1) >> LOG_WIN)   // 7

// ---------------- bf16 (storage) <-> f32 (math) ----------------

__device__ inline float ldh(const unsigned short* p) {
    unsigned int u = ((unsigned int)*p) << 16;
    float f; __builtin_memcpy(&f, &u, 4); return f;
}
__device__ inline void sth(unsigned short* p, float v) {
    unsigned int b; __builtin_memcpy(&b, &v, 4);
    unsigned int r = (b + 0x7FFFu + ((b >> 16) & 1u)) >> 16;   // RNE
    *p = (unsigned short)r;
}
__device__ inline float bflo(unsigned int d) { return __uint_as_float(d << 16); }
__device__ inline float bfhi(unsigned int d) { return __uint_as_float(d & 0xFFFF0000u); }

__device__ inline int clampi(int v, int lo, int hi) {
    return v < lo ? lo : (v > hi ? hi : v);
}

// ---------------- utility ----------------

__global__ void k_zero(int* __restrict__ p, int n) {
    int i = blockIdx.x * blockDim.x + threadIdx.x;
    if (i < n) p[i] = 0;
}

// ---------------- CSR construction ----------------

__global__ void k_count(const int* __restrict__ ei, int* __restrict__ deg) {
    int e = blockIdx.x * blockDim.x + threadIdx.x;
    if (e < N_EDGES) {
        int d = clampi(ei[N_EDGES + e], 0, N_NODES - 1);
        atomicAdd(&deg[d], 1);
    }
}

__global__ void k_scan(const int* __restrict__ deg, int* __restrict__ off) {
    const int T = 1024;
    const int chunk = (N_NODES + T - 1) / T;   // 98
    __shared__ int sums[T];
    __shared__ int pref[T];
    int t = threadIdx.x;
    int base = t * chunk;
    int s = 0;
    for (int i = 0; i < chunk; ++i) {
        int idx = base + i;
        if (idx < N_NODES) s += deg[idx];
    }
    sums[t] = s;
    __syncthreads();
    if (t == 0) {
        int run = 0;
        for (int i = 0; i < T; ++i) { pref[i] = run; run += sums[i]; }
    }
    __syncthreads();
    int run = pref[t];
    for (int i = 0; i < chunk; ++i) {
        int idx = base + i;
        if (idx < N_NODES) { off[idx] = run; run += deg[idx]; }
    }
    if (t == T - 1) off[N_NODES] = pref[T - 1] + sums[T - 1];
}

__global__ void k_copy_int(const int* __restrict__ a, int* __restrict__ b, int n) {
    int i = blockIdx.x * blockDim.x + threadIdx.x;
    if (i < n) b[i] = a[i];
}

// dst-windowed fill: keeps adj scatter writes inside a ~2MB window (L2-resident)
__global__ void k_fill(const int* __restrict__ ei, int* __restrict__ cur,
                       int* __restrict__ adj) {
    int e = blockIdx.x * blockDim.x + threadIdx.x;
    int p = blockIdx.y;
    if (e < N_EDGES) {
        int d = clampi(ei[N_EDGES + e], 0, N_NODES - 1);
        if ((d >> LOG_WIN) == p) {
            int s = clampi(ei[e], 0, N_NODES - 1);
            int q = atomicAdd(&cur[d], 1);
            if (q >= 0 && q < N_EDGES) adj[q] = s;
        }
    }
}

// ---------------- Layer 1 (F_IN = 3) ----------------

__global__ __launch_bounds__(256) void k_layer1(
        const float* __restrict__ x, const int* __restrict__ off,
        const int* __restrict__ adj, const float* __restrict__ epsp,
        const float* __restrict__ W1, const float* __restrict__ b1,
        unsigned short* __restrict__ hout) {
    int wid  = (blockIdx.x * blockDim.x + threadIdx.x) >> 6;   // node
    int lane = threadIdx.x & 63;
    if (wid >= N_NODES) return;
    int o0 = off[wid], o1 = off[wid + 1];
    float a0 = 0.f, a1 = 0.f, a2 = 0.f;
    for (int e = o0 + lane; e < o1; e += 64) {
        int s = adj[e];
        a0 += x[s * 3 + 0];
        a1 += x[s * 3 + 1];
        a2 += x[s * 3 + 2];
    }
    #pragma unroll
    for (int d = 32; d; d >>= 1) {
        a0 += __shfl_xor(a0, d);
        a1 += __shfl_xor(a1, d);
        a2 += __shfl_xor(a2, d);
    }
    float ep = 1.0f + epsp[0];
    float s0 = ep * x[wid * 3 + 0] + a0;
    float s1 = ep * x[wid * 3 + 1] + a1;
    float s2 = ep * x[wid * 3 + 2] + a2;
    float o = b1[lane] + s0 * W1[lane] + s1 * W1[64 + lane] + s2 * W1[128 + lane];
    sth(&hout[(size_t)wid * 64 + lane], fmaxf(o, 0.f));
}

// ---------------- fused aggregation (quad-packed) + 64x64 matmul ----------------
// One wave per node. Feature row = 128B bf16 = 16 uint2. Lane layout:
//   q  = lane&15  -> feature quad {4q..4q+3} (uint2 = 4 bf16)
//   g4 = lane>>4  -> neighbor subgroup (4 neighbor rows per load instruction)
// 8 unrolled quad-steps = 32 neighbor rows in flight per wave.

__device__ inline float node_forward(
        const unsigned short* __restrict__ hin, const int* __restrict__ off,
        const int* __restrict__ adj, float ep,
        const float* __restrict__ Wl, const float* __restrict__ bl,
        int wid, int lane) {
    const uint2* h2 = (const uint2*)hin;   // 16 uint2 per 64-feature row
    int q  = lane & 15;
    int g4 = lane >> 4;
    float a0 = 0.f, a1 = 0.f, a2 = 0.f, a3 = 0.f;
    int o0 = off[wid], o1 = off[wid + 1];
    for (int base = o0; base < o1; base += 64) {
        int n = o1 - base; n = n < 64 ? n : 64;
        int li = lane < n ? lane : n - 1;
        int idx = adj[base + li];            // one coalesced read per 64 edges
        int quads = (n + 3) >> 2;            // <= 16
        for (int p0 = 0; p0 < quads; p0 += 8) {
            uint2 d0, d1, d2, d3, d4, d5, d6, d7;
            int  v0, v1, v2, v3, v4, v5, v6, v7;
            #pragma unroll
            for (int i = 0; i < 8; ++i) {
                int pp = p0 + i;
                int sl = (pp << 2) + g4;          // < 64 guaranteed (quads<=16)
                int s  = __shfl(idx, sl);          // per-lane src -> bpermute
                uint2 d = h2[(size_t)s * 16 + q];  // 8B x 64 lanes = 4 rows
                int ok = sl < n;
                if (i == 0) { d0 = d; v0 = ok; } else if (i == 1) { d1 = d; v1 = ok; }
                else if (i == 2) { d2 = d; v2 = ok; } else if (i == 3) { d3 = d; v3 = ok; }
                else if (i == 4) { d4 = d; v4 = ok; } else if (i == 5) { d5 = d; v5 = ok; }
                else if (i == 6) { d6 = d; v6 = ok; } else { d7 = d; v7 = ok; }
            }
            #pragma unroll
            for (int i = 0; i < 8; ++i) {
                uint2 d = (i == 0) ? d0 : (i == 1) ? d1 : (i == 2) ? d2 : (i == 3) ? d3
                        : (i == 4) ? d4 : (i == 5) ? d5 : (i == 6) ? d6 : d7;
                int ok  = (i == 0) ? v0 : (i == 1) ? v1 : (i == 2) ? v2 : (i == 3) ? v3
                        : (i == 4) ? v4 : (i == 5) ? v5 : (i == 6) ? v6 : v7;
                unsigned int lo = ok ? d.x : 0u;
                unsigned int hc = ok ? d.y : 0u;
                a0 += bflo(lo); a1 += bfhi(lo);
                a2 += bflo(hc); a3 += bfhi(hc);
            }
        }
    }
    // reduce the 4 neighbor subgroups
    a0 += __shfl_xor(a0, 16); a1 += __shfl_xor(a1, 16);
    a2 += __shfl_xor(a2, 16); a3 += __shfl_xor(a3, 16);
    a0 += __shfl_xor(a0, 32); a1 += __shfl_xor(a1, 32);
    a2 += __shfl_xor(a2, 32); a3 += __shfl_xor(a3, 32);
    // self term (every lane loads its quad of the self row; counted once)
    uint2 ds = h2[(size_t)wid * 16 + q];
    a0 += ep * bflo(ds.x); a1 += ep * bfhi(ds.x);
    a2 += ep * bflo(ds.y); a3 += ep * bfhi(ds.y);
    // matmul: feature k lives at lane k>>2, component k&3 (uniform src -> readlane)
    float acc = bl[lane];
    #pragma unroll
    for (int k = 0; k < 64; ++k) {
        float comp = ((k & 3) == 0) ? a0 : ((k & 3) == 1) ? a1 : ((k & 3) == 2) ? a2 : a3;
        float fk = __shfl(comp, k >> 2);
        acc += fk * Wl[k * 64 + lane];
    }
    return fmaxf(acc, 0.f);
}

__global__ __launch_bounds__(1024) void k_layer(
        const unsigned short* __restrict__ hin, const int* __restrict__ off,
        const int* __restrict__ adj, const float* __restrict__ epsp,
        const float* __restrict__ W, const float* __restrict__ b,
        unsigned short* __restrict__ hout) {
    __shared__ float Wl[64 * 64];
    __shared__ float bl[64];
    for (int i = threadIdx.x; i < 64 * 64; i += 1024) Wl[i] = W[i];
    if (threadIdx.x < 64) bl[threadIdx.x] = b[threadIdx.x];
    __syncthreads();
    int wid  = (blockIdx.x * blockDim.x + threadIdx.x) >> 6;   // exact: no tail
    int lane = threadIdx.x & 63;
    float r = node_forward(hin, off, adj, 1.0f + epsp[0], Wl, bl, wid, lane);
    sth(&hout[(size_t)wid * 64 + lane], r);
}

// layer 3 + pooling with LDS pre-aggregation (batch is sorted by graph)
__global__ __launch_bounds__(1024) void k_layer_pool(
        const unsigned short* __restrict__ hin, const int* __restrict__ off,
        const int* __restrict__ adj, const float* __restrict__ epsp,
        const float* __restrict__ W, const float* __restrict__ b,
        const int* __restrict__ batch,
        float* __restrict__ pooled, int* __restrict__ cnt) {
    __shared__ float Wl[64 * 64];
    __shared__ float bl[64];
    __shared__ float sacc[8 * 64];
    __shared__ int   scnt[8];
    for (int i = threadIdx.x; i < 64 * 64; i += 1024) Wl[i] = W[i];
    if (threadIdx.x < 64) bl[threadIdx.x] = b[threadIdx.x];
    for (int i = threadIdx.x; i < 8 * 64; i += 1024) sacc[i] = 0.f;
    if (threadIdx.x < 8) scnt[threadIdx.x] = 0;
    __syncthreads();
    int wid  = (blockIdx.x * blockDim.x + threadIdx.x) >> 6;   // exact: no tail
    int lane = threadIdx.x & 63;
    float r = node_forward(hin, off, adj, 1.0f + epsp[0], Wl, bl, wid, lane);
    int g  = clampi(batch[wid], 0, N_GRAPHS - 1);
    int g0 = clampi(batch[blockIdx.x << 4], 0, N_GRAPHS - 1);
    int og = g - g0;                         // >=0 (sorted batch)
    if (og >= 0 && og < 8) {
        atomicAdd(&sacc[og * 64 + lane], r);
        if (lane == 0) atomicAdd(&scnt[og], 1);
    } else {
        atomicAdd(&pooled[g * 64 + lane], r);
        if (lane == 0) atomicAdd(&cnt[g], 1);
    }
    __syncthreads();
    int w = threadIdx.x >> 6;                // wave id; waves 0..7 flush slots
    if (w < 8) {
        int c = scnt[w];
        if (c > 0) {
            atomicAdd(&pooled[(g0 + w) * 64 + lane], sacc[w * 64 + lane]);
            if (lane == 0) atomicAdd(&cnt[g0 + w], c);
        }
    }
}

// ---------------- Head: mean, 64->10 relu, 10->1 ----------------

__global__ __launch_bounds__(256) void k_head(
        const float* __restrict__ pooled, const int* __restrict__ cnt,
        const float* __restrict__ Wf1, const float* __restrict__ bf1,
        const float* __restrict__ Wf2, const float* __restrict__ bf2,
        float* __restrict__ out) {
    int g = blockIdx.x * blockDim.x + threadIdx.x;
    if (g >= N_GRAPHS) return;
    float inv = 1.0f / fmaxf((float)cnt[g], 1.0f);
    float p[64];
    #pragma unroll
    for (int k = 0; k < 64; ++k) p[k] = pooled[g * 64 + k] * inv;
    float o = bf2[0];
    #pragma unroll
    for (int j = 0; j < 10; ++j) {
        float s = bf1[j];
        #pragma unroll
        for (int k = 0; k < 64; ++k) s += p[k] * Wf1[k * 10 + j];
        o += fmaxf(s, 0.f) * Wf2[j];
    }
    out[g] = o;
}

// ---------------- launch ----------------

extern "C" void kernel_launch(void* const* d_in, const int* in_sizes, int n_in,
                              void* d_out, int out_size, void* d_ws, size_t ws_size,
                              hipStream_t stream) {
    const float* x     = (const float*)d_in[0];
    const int*   ei    = (const int*)d_in[1];    // int64 in ref -> int32 on device
    const int*   batch = (const int*)d_in[2];
    const float* eps1 = (const float*)d_in[3];
    const float* eps2 = (const float*)d_in[4];
    const float* eps3 = (const float*)d_in[5];
    const float* W1 = (const float*)d_in[6];
    const float* b1 = (const float*)d_in[7];
    const float* W2 = (const float*)d_in[8];
    const float* b2 = (const float*)d_in[9];
    const float* W3 = (const float*)d_in[10];
    const float* b3 = (const float*)d_in[11];
    const float* Wf1 = (const float*)d_in[12];
    const float* bf1 = (const float*)d_in[13];
    const float* Wf2 = (const float*)d_in[14];
    const float* bf2 = (const float*)d_in[15];
    float* out = (float*)d_out;

    const size_t H64 = (size_t)N_NODES * HDIM;          // 6,400,000 elems

    char* base = (char*)d_ws;
    unsigned short* hA = (unsigned short*)base;                    // 12.8 MB
    unsigned short* hB = (unsigned short*)(base + H64 * 2);        // 12.8 MB
    char* q = base + 2 * H64 * 2;
    float* pooled = (float*)q;            q += 64000ull * 4;
    int*   cnt    = (int*)q;              q += 1000ull * 4;
    int*   deg    = (int*)q;              q += 100000ull * 4;
    int*   off    = (int*)q;              q += 100004ull * 4;
    int*   adj    = (int*)q;

    const int TB = 256;
    k_zero<<<(N_NODES + TB - 1) / TB, TB, 0, stream>>>(deg, N_NODES);
    k_zero<<<(65000 + TB - 1) / TB, TB, 0, stream>>>((int*)pooled, 65000);

    // CSR build: single-pass count, windowed fill
    k_count<<<(N_EDGES + TB - 1) / TB, TB, 0, stream>>>(ei, deg);
    k_scan<<<1, 1024, 0, stream>>>(deg, off);
    k_copy_int<<<(N_NODES + TB - 1) / TB, TB, 0, stream>>>(off, deg, N_NODES);
    dim3 egrid((N_EDGES + TB - 1) / TB, NPASS);
    k_fill<<<egrid, TB, 0, stream>>>(ei, deg, adj);

    const int L1_BLOCKS = (int)((H64 + TB - 1) / TB);        // 4 nodes/block @256
    const int LBLOCKS   = N_NODES / 16;                      // 16 nodes/block @1024 (exact)

    k_layer1<<<L1_BLOCKS, TB, 0, stream>>>(x, off, adj, eps1, W1, b1, hA);
    k_layer<<<LBLOCKS, 1024, 0, stream>>>(hA, off, adj, eps2, W2, b2, hB);
    k_layer_pool<<<LBLOCKS, 1024, 0, stream>>>(hB, off, adj, eps3, W3, b3,
                                               batch, pooled, cnt);

    k_head<<<(N_GRAPHS + TB - 1) / TB, TB, 0, stream>>>(pooled, cnt, Wf1, bf1, Wf2, bf2, out);
}

// Round 7
// 647.529 us; speedup vs baseline: 2.0909x; 1.2977x over previous
//
#include <hip/hip_runtime.h>

#define N_NODES  100000
#define N_EDGES  3200000
#define N_GRAPHS 1000
#define HDIM     64

#define LOG_WIN  14                       // dst window for k_fill = 16384 nodes
#define NPASS    ((N_NODES + (1 << LOG_WIN) - 1) >> LOG_WIN)   // 7
#define SCAN_B   1024
#define NBLK     ((N_NODES + SCAN_B - 1) / SCAN_B)             // 98

// ---------------- bf16 (storage) <-> f32 (math) ----------------

__device__ inline void sth(unsigned short* p, float v) {
    unsigned int b; __builtin_memcpy(&b, &v, 4);
    unsigned int r = (b + 0x7FFFu + ((b >> 16) & 1u)) >> 16;   // RNE
    *p = (unsigned short)r;
}
__device__ inline float bflo(unsigned int d) { return __uint_as_float(d << 16); }
__device__ inline float bfhi(unsigned int d) { return __uint_as_float(d & 0xFFFF0000u); }

__device__ inline int clampi(int v, int lo, int hi) {
    return v < lo ? lo : (v > hi ? hi : v);
}

// ---------------- utility ----------------

__global__ void k_zero(int* __restrict__ p, int n) {
    int i = blockIdx.x * blockDim.x + threadIdx.x;
    if (i < n) p[i] = 0;
}

// ---------------- CSR construction ----------------

__global__ void k_count(const int* __restrict__ ei, int* __restrict__ deg) {
    int e = blockIdx.x * blockDim.x + threadIdx.x;
    if (e < N_EDGES) {
        int d = clampi(ei[N_EDGES + e], 0, N_NODES - 1);
        atomicAdd(&deg[d], 1);
    }
}

// two-level parallel exclusive scan over deg -> off, also fills cursor
__global__ __launch_bounds__(SCAN_B) void k_scan1(
        const int* __restrict__ deg, int* __restrict__ off, int* __restrict__ bsum) {
    __shared__ int s[SCAN_B];
    int t = threadIdx.x;
    int i = blockIdx.x * SCAN_B + t;
    int v = (i < N_NODES) ? deg[i] : 0;
    s[t] = v;
    __syncthreads();
    #pragma unroll
    for (int d = 1; d < SCAN_B; d <<= 1) {
        int add = (t >= d) ? s[t - d] : 0;
        __syncthreads();
        s[t] += add;
        __syncthreads();
    }
    if (i < N_NODES) off[i] = s[t] - v;          // exclusive within block
    if (t == SCAN_B - 1) bsum[blockIdx.x] = s[t];
}

__global__ void k_scan2(int* __restrict__ bsum) {
    __shared__ int s[NBLK + 1];
    int t = threadIdx.x;
    if (t < NBLK) s[t] = bsum[t];
    __syncthreads();
    if (t == 0) {
        int run = 0;
        for (int i = 0; i < NBLK; ++i) { int x = s[i]; s[i] = run; run += x; }
        s[NBLK] = run;
    }
    __syncthreads();
    if (t <= NBLK) bsum[t] = s[t];
}

__global__ __launch_bounds__(SCAN_B) void k_scan3(
        int* __restrict__ off, int* __restrict__ cur, const int* __restrict__ bsum) {
    int i = blockIdx.x * SCAN_B + threadIdx.x;
    if (i < N_NODES) {
        int v = off[i] + bsum[blockIdx.x];
        off[i] = v;
        cur[i] = v;
    }
    if (i == 0) off[N_NODES] = bsum[NBLK];       // total
}

// dst-windowed fill: keeps adj scatter writes inside a ~2MB window (L2-resident)
__global__ void k_fill(const int* __restrict__ ei, int* __restrict__ cur,
                       int* __restrict__ adj) {
    int e = blockIdx.x * blockDim.x + threadIdx.x;
    int p = blockIdx.y;
    if (e < N_EDGES) {
        int d = clampi(ei[N_EDGES + e], 0, N_NODES - 1);
        if ((d >> LOG_WIN) == p) {
            int s = clampi(ei[e], 0, N_NODES - 1);
            int q = atomicAdd(&cur[d], 1);
            if (q >= 0 && q < N_EDGES) adj[q] = s;
        }
    }
}

// ---------------- Layer 1 (F_IN = 3) ----------------

__global__ __launch_bounds__(256) void k_layer1(
        const float* __restrict__ x, const int* __restrict__ off,
        const int* __restrict__ adj, const float* __restrict__ epsp,
        const float* __restrict__ W1, const float* __restrict__ b1,
        unsigned short* __restrict__ hout) {
    int wid  = (blockIdx.x * blockDim.x + threadIdx.x) >> 6;   // node
    int lane = threadIdx.x & 63;
    if (wid >= N_NODES) return;
    int o0 = off[wid], o1 = off[wid + 1];
    float a0 = 0.f, a1 = 0.f, a2 = 0.f;
    for (int e = o0 + lane; e < o1; e += 64) {
        int s = adj[e];
        a0 += x[s * 3 + 0];
        a1 += x[s * 3 + 1];
        a2 += x[s * 3 + 2];
    }
    #pragma unroll
    for (int d = 32; d; d >>= 1) {
        a0 += __shfl_xor(a0, d);
        a1 += __shfl_xor(a1, d);
        a2 += __shfl_xor(a2, d);
    }
    float ep = 1.0f + epsp[0];
    float s0 = ep * x[wid * 3 + 0] + a0;
    float s1 = ep * x[wid * 3 + 1] + a1;
    float s2 = ep * x[wid * 3 + 2] + a2;
    float o = b1[lane] + s0 * W1[lane] + s1 * W1[64 + lane] + s2 * W1[128 + lane];
    sth(&hout[(size_t)wid * 64 + lane], fmaxf(o, 0.f));
}

// ---------------- fused aggregation (quad-packed) + 64x64 matmul ----------------
// One wave per node. Feature row = 128B bf16 = 16 uint2. Lane layout:
//   q  = lane&15  -> feature quad {4q..4q+3} (uint2 = 4 bf16)
//   g4 = lane>>4  -> neighbor subgroup (4 neighbor rows per load instruction)

__device__ inline float node_forward(
        const unsigned short* __restrict__ hin, const int* __restrict__ off,
        const int* __restrict__ adj, float ep,
        const float* __restrict__ Wl, const float* __restrict__ bl,
        int wid, int lane) {
    const uint2* h2 = (const uint2*)hin;   // 16 uint2 per 64-feature row
    int q  = lane & 15;
    int g4 = lane >> 4;
    float a0 = 0.f, a1 = 0.f, a2 = 0.f, a3 = 0.f;
    int o0 = off[wid], o1 = off[wid + 1];
    for (int base = o0; base < o1; base += 64) {
        int n = o1 - base; n = n < 64 ? n : 64;
        int li = lane < n ? lane : n - 1;
        int idx = adj[base + li];            // one coalesced read per 64 edges
        int quads = (n + 3) >> 2;            // <= 16
        for (int p0 = 0; p0 < quads; p0 += 8) {
            uint2 d0, d1, d2, d3, d4, d5, d6, d7;
            int  v0, v1, v2, v3, v4, v5, v6, v7;
            #pragma unroll
            for (int i = 0; i < 8; ++i) {
                int pp = p0 + i;
                int sl = (pp << 2) + g4;          // < 64 guaranteed (quads<=16)
                int s  = __shfl(idx, sl);          // per-lane src -> bpermute
                uint2 d = h2[(size_t)s * 16 + q];  // 8B x 64 lanes = 4 rows
                int ok = sl < n;
                if (i == 0) { d0 = d; v0 = ok; } else if (i == 1) { d1 = d; v1 = ok; }
                else if (i == 2) { d2 = d; v2 = ok; } else if (i == 3) { d3 = d; v3 = ok; }
                else if (i == 4) { d4 = d; v4 = ok; } else if (i == 5) { d5 = d; v5 = ok; }
                else if (i == 6) { d6 = d; v6 = ok; } else { d7 = d; v7 = ok; }
            }
            #pragma unroll
            for (int i = 0; i < 8; ++i) {
                uint2 d = (i == 0) ? d0 : (i == 1) ? d1 : (i == 2) ? d2 : (i == 3) ? d3
                        : (i == 4) ? d4 : (i == 5) ? d5 : (i == 6) ? d6 : d7;
                int ok  = (i == 0) ? v0 : (i == 1) ? v1 : (i == 2) ? v2 : (i == 3) ? v3
                        : (i == 4) ? v4 : (i == 5) ? v5 : (i == 6) ? v6 : v7;
                unsigned int lo = ok ? d.x : 0u;
                unsigned int hc = ok ? d.y : 0u;
                a0 += bflo(lo); a1 += bfhi(lo);
                a2 += bflo(hc); a3 += bfhi(hc);
            }
        }
    }
    // reduce the 4 neighbor subgroups
    a0 += __shfl_xor(a0, 16); a1 += __shfl_xor(a1, 16);
    a2 += __shfl_xor(a2, 16); a3 += __shfl_xor(a3, 16);
    a0 += __shfl_xor(a0, 32); a1 += __shfl_xor(a1, 32);
    a2 += __shfl_xor(a2, 32); a3 += __shfl_xor(a3, 32);
    // self term
    uint2 ds = h2[(size_t)wid * 16 + q];
    a0 += ep * bflo(ds.x); a1 += ep * bfhi(ds.x);
    a2 += ep * bflo(ds.y); a3 += ep * bfhi(ds.y);
    // matmul: feature k lives at lane k>>2, component k&3
    float acc = bl[lane];
    #pragma unroll
    for (int k = 0; k < 64; ++k) {
        float comp = ((k & 3) == 0) ? a0 : ((k & 3) == 1) ? a1 : ((k & 3) == 2) ? a2 : a3;
        float fk = __shfl(comp, k >> 2);
        acc += fk * Wl[k * 64 + lane];
    }
    return fmaxf(acc, 0.f);
}

__global__ __launch_bounds__(1024) void k_layer(
        const unsigned short* __restrict__ hin, const int* __restrict__ off,
        const int* __restrict__ adj, const float* __restrict__ epsp,
        const float* __restrict__ W, const float* __restrict__ b,
        unsigned short* __restrict__ hout) {
    __shared__ float Wl[64 * 64];
    __shared__ float bl[64];
    for (int i = threadIdx.x; i < 64 * 64; i += 1024) Wl[i] = W[i];
    if (threadIdx.x < 64) bl[threadIdx.x] = b[threadIdx.x];
    __syncthreads();
    int wid  = (blockIdx.x * blockDim.x + threadIdx.x) >> 6;   // exact: no tail
    int lane = threadIdx.x & 63;
    float r = node_forward(hin, off, adj, 1.0f + epsp[0], Wl, bl, wid, lane);
    sth(&hout[(size_t)wid * 64 + lane], r);
}

// layer 3 + pooling with LDS pre-aggregation (batch is sorted by graph)
__global__ __launch_bounds__(1024) void k_layer_pool(
        const unsigned short* __restrict__ hin, const int* __restrict__ off,
        const int* __restrict__ adj, const float* __restrict__ epsp,
        const float* __restrict__ W, const float* __restrict__ b,
        const int* __restrict__ batch,
        float* __restrict__ pooled, int* __restrict__ cnt) {
    __shared__ float Wl[64 * 64];
    __shared__ float bl[64];
    __shared__ float sacc[8 * 64];
    __shared__ int   scnt[8];
    for (int i = threadIdx.x; i < 64 * 64; i += 1024) Wl[i] = W[i];
    if (threadIdx.x < 64) bl[threadIdx.x] = b[threadIdx.x];
    for (int i = threadIdx.x; i < 8 * 64; i += 1024) sacc[i] = 0.f;
    if (threadIdx.x < 8) scnt[threadIdx.x] = 0;
    __syncthreads();
    int wid  = (blockIdx.x * blockDim.x + threadIdx.x) >> 6;   // exact: no tail
    int lane = threadIdx.x & 63;
    float r = node_forward(hin, off, adj, 1.0f + epsp[0], Wl, bl, wid, lane);
    int g  = clampi(batch[wid], 0, N_GRAPHS - 1);
    int g0 = clampi(batch[blockIdx.x << 4], 0, N_GRAPHS - 1);
    int og = g - g0;                         // >=0 (sorted batch)
    if (og >= 0 && og < 8) {
        atomicAdd(&sacc[og * 64 + lane], r);
        if (lane == 0) atomicAdd(&scnt[og], 1);
    } else {
        atomicAdd(&pooled[g * 64 + lane], r);
        if (lane == 0) atomicAdd(&cnt[g], 1);
    }
    __syncthreads();
    int w = threadIdx.x >> 6;                // waves 0..7 flush slots
    if (w < 8) {
        int c = scnt[w];
        if (c > 0) {
            atomicAdd(&pooled[(g0 + w) * 64 + lane], sacc[w * 64 + lane]);
            if (lane == 0) atomicAdd(&cnt[g0 + w], c);
        }
    }
}

// ---------------- Head: mean, 64->10 relu, 10->1 ----------------

__global__ __launch_bounds__(256) void k_head(
        const float* __restrict__ pooled, const int* __restrict__ cnt,
        const float* __restrict__ Wf1, const float* __restrict__ bf1,
        const float* __restrict__ Wf2, const float* __restrict__ bf2,
        float* __restrict__ out) {
    int g = blockIdx.x * blockDim.x + threadIdx.x;
    if (g >= N_GRAPHS) return;
    float inv = 1.0f / fmaxf((float)cnt[g], 1.0f);
    float p[64];
    #pragma unroll
    for (int k = 0; k < 64; ++k) p[k] = pooled[g * 64 + k] * inv;
    float o = bf2[0];
    #pragma unroll
    for (int j = 0; j < 10; ++j) {
        float s = bf1[j];
        #pragma unroll
        for (int k = 0; k < 64; ++k) s += p[k] * Wf1[k * 10 + j];
        o += fmaxf(s, 0.f) * Wf2[j];
    }
    out[g] = o;
}

// ---------------- launch ----------------

extern "C" void kernel_launch(void* const* d_in, const int* in_sizes, int n_in,
                              void* d_out, int out_size, void* d_ws, size_t ws_size,
                              hipStream_t stream) {
    const float* x     = (const float*)d_in[0];
    const int*   ei    = (const int*)d_in[1];    // int64 in ref -> int32 on device
    const int*   batch = (const int*)d_in[2];
    const float* eps1 = (const float*)d_in[3];
    const float* eps2 = (const float*)d_in[4];
    const float* eps3 = (const float*)d_in[5];
    const float* W1 = (const float*)d_in[6];
    const float* b1 = (const float*)d_in[7];
    const float* W2 = (const float*)d_in[8];
    const float* b2 = (const float*)d_in[9];
    const float* W3 = (const float*)d_in[10];
    const float* b3 = (const float*)d_in[11];
    const float* Wf1 = (const float*)d_in[12];
    const float* bf1 = (const float*)d_in[13];
    const float* Wf2 = (const float*)d_in[14];
    const float* bf2 = (const float*)d_in[15];
    float* out = (float*)d_out;

    const size_t H64 = (size_t)N_NODES * HDIM;          // 6,400,000 elems

    char* base = (char*)d_ws;
    unsigned short* hA = (unsigned short*)base;                    // 12.8 MB
    unsigned short* hB = (unsigned short*)(base + H64 * 2);        // 12.8 MB
    char* q = base + 2 * H64 * 2;
    float* pooled = (float*)q;            q += 64000ull * 4;
    int*   cnt    = (int*)q;              q += 1000ull * 4;
    int*   deg    = (int*)q;              q += 100000ull * 4;
    int*   off    = (int*)q;              q += 100004ull * 4;
    int*   bsum   = (int*)q;              q += 128ull * 4;
    int*   adj    = (int*)q;

    const int TB = 256;
    k_zero<<<(N_NODES + TB - 1) / TB, TB, 0, stream>>>(deg, N_NODES);
    k_zero<<<(65000 + TB - 1) / TB, TB, 0, stream>>>((int*)pooled, 65000);

    // CSR build: count -> two-level scan (also fills cursor in deg) -> windowed fill
    k_count<<<(N_EDGES + TB - 1) / TB, TB, 0, stream>>>(ei, deg);
    k_scan1<<<NBLK, SCAN_B, 0, stream>>>(deg, off, bsum);
    k_scan2<<<1, 128, 0, stream>>>(bsum);
    k_scan3<<<NBLK, SCAN_B, 0, stream>>>(off, deg, bsum);   // deg becomes cursor
    dim3 egrid((N_EDGES + TB - 1) / TB, NPASS);
    k_fill<<<egrid, TB, 0, stream>>>(ei, deg, adj);

    const int L1_BLOCKS = (int)((H64 + TB - 1) / TB);        // 4 nodes/block @256
    const int LBLOCKS   = N_NODES / 16;                      // 16 nodes/block @1024 (exact)

    k_layer1<<<L1_BLOCKS, TB, 0, stream>>>(x, off, adj, eps1, W1, b1, hA);
    k_layer<<<LBLOCKS, 1024, 0, stream>>>(hA, off, adj, eps2, W2, b2, hB);
    k_layer_pool<<<LBLOCKS, 1024, 0, stream>>>(hB, off, adj, eps3, W3, b3,
                                               batch, pooled, cnt);

    k_head<<<(N_GRAPHS + TB - 1) / TB, TB, 0, stream>>>(pooled, cnt, Wf1, bf1, Wf2, bf2, out);
}

// Round 8
// 483.742 us; speedup vs baseline: 2.7989x; 1.3386x over previous
//
#include <hip/hip_runtime.h>

#define N_NODES  100000
#define N_EDGES  3200000
#define N_GRAPHS 1000
#define HDIM     64

#define LOG_WIN  14                       // dst window for k_fill = 16384 nodes
#define NPASS    ((N_NODES + (1 << LOG_WIN) - 1) >> LOG_WIN)   // 7
#define SCAN_B   1024
#define NBLK     ((N_NODES + SCAN_B - 1) / SCAN_B)             // 98

typedef __attribute__((ext_vector_type(8))) short short8;
typedef __attribute__((ext_vector_type(4))) float f32x4;

// ---------------- bf16 (storage) <-> f32 (math) ----------------

__device__ inline unsigned short f2bf(float v) {
    unsigned int b; __builtin_memcpy(&b, &v, 4);
    return (unsigned short)((b + 0x7FFFu + ((b >> 16) & 1u)) >> 16);   // RNE
}
__device__ inline float bf2f(unsigned short u) {
    return __uint_as_float(((unsigned int)u) << 16);
}
__device__ inline void sth(unsigned short* p, float v) { *p = f2bf(v); }
__device__ inline float bflo(unsigned int d) { return __uint_as_float(d << 16); }
__device__ inline float bfhi(unsigned int d) { return __uint_as_float(d & 0xFFFF0000u); }

__device__ inline int clampi(int v, int lo, int hi) {
    return v < lo ? lo : (v > hi ? hi : v);
}

// ---------------- utility ----------------

__global__ void k_zero(int* __restrict__ p, int n) {
    int i = blockIdx.x * blockDim.x + threadIdx.x;
    if (i < n) p[i] = 0;
}

// ---------------- CSR construction ----------------

__global__ void k_count(const int* __restrict__ ei, int* __restrict__ deg) {
    int e = blockIdx.x * blockDim.x + threadIdx.x;
    if (e < N_EDGES) {
        int d = clampi(ei[N_EDGES + e], 0, N_NODES - 1);
        atomicAdd(&deg[d], 1);
    }
}

__global__ __launch_bounds__(SCAN_B) void k_scan1(
        const int* __restrict__ deg, int* __restrict__ off, int* __restrict__ bsum) {
    __shared__ int s[SCAN_B];
    int t = threadIdx.x;
    int i = blockIdx.x * SCAN_B + t;
    int v = (i < N_NODES) ? deg[i] : 0;
    s[t] = v;
    __syncthreads();
    #pragma unroll
    for (int d = 1; d < SCAN_B; d <<= 1) {
        int add = (t >= d) ? s[t - d] : 0;
        __syncthreads();
        s[t] += add;
        __syncthreads();
    }
    if (i < N_NODES) off[i] = s[t] - v;          // exclusive within block
    if (t == SCAN_B - 1) bsum[blockIdx.x] = s[t];
}

__global__ void k_scan2(int* __restrict__ bsum) {
    __shared__ int s[NBLK + 1];
    int t = threadIdx.x;
    if (t < NBLK) s[t] = bsum[t];
    __syncthreads();
    if (t == 0) {
        int run = 0;
        for (int i = 0; i < NBLK; ++i) { int x = s[i]; s[i] = run; run += x; }
        s[NBLK] = run;
    }
    __syncthreads();
    if (t <= NBLK) bsum[t] = s[t];
}

__global__ __launch_bounds__(SCAN_B) void k_scan3(
        int* __restrict__ off, int* __restrict__ cur, const int* __restrict__ bsum) {
    int i = blockIdx.x * SCAN_B + threadIdx.x;
    if (i < N_NODES) {
        int v = off[i] + bsum[blockIdx.x];
        off[i] = v;
        cur[i] = v;
    }
    if (i == 0) off[N_NODES] = bsum[NBLK];       // total
}

__global__ void k_fill(const int* __restrict__ ei, int* __restrict__ cur,
                       int* __restrict__ adj) {
    int e = blockIdx.x * blockDim.x + threadIdx.x;
    int p = blockIdx.y;
    if (e < N_EDGES) {
        int d = clampi(ei[N_EDGES + e], 0, N_NODES - 1);
        if ((d >> LOG_WIN) == p) {
            int s = clampi(ei[e], 0, N_NODES - 1);
            int q = atomicAdd(&cur[d], 1);
            if (q >= 0 && q < N_EDGES) adj[q] = s;
        }
    }
}

// ---------------- Layer 1 (F_IN = 3): fused agg + 3x64 matmul ----------------

__global__ __launch_bounds__(256) void k_layer1(
        const float* __restrict__ x, const int* __restrict__ off,
        const int* __restrict__ adj, const float* __restrict__ epsp,
        const float* __restrict__ W1, const float* __restrict__ b1,
        unsigned short* __restrict__ hout) {
    int wid  = (blockIdx.x * blockDim.x + threadIdx.x) >> 6;   // node
    int lane = threadIdx.x & 63;
    if (wid >= N_NODES) return;
    int o0 = off[wid], o1 = off[wid + 1];
    float a0 = 0.f, a1 = 0.f, a2 = 0.f;
    for (int e = o0 + lane; e < o1; e += 64) {
        int s = adj[e];
        a0 += x[s * 3 + 0];
        a1 += x[s * 3 + 1];
        a2 += x[s * 3 + 2];
    }
    #pragma unroll
    for (int d = 32; d; d >>= 1) {
        a0 += __shfl_xor(a0, d);
        a1 += __shfl_xor(a1, d);
        a2 += __shfl_xor(a2, d);
    }
    float ep = 1.0f + epsp[0];
    float s0 = ep * x[wid * 3 + 0] + a0;
    float s1 = ep * x[wid * 3 + 1] + a1;
    float s2 = ep * x[wid * 3 + 2] + a2;
    float o = b1[lane] + s0 * W1[lane] + s1 * W1[64 + lane] + s2 * W1[128 + lane];
    sth(&hout[(size_t)wid * 64 + lane], fmaxf(o, 0.f));
}

// ---------------- Dense GEMM: Y = h @ W  (100000x64 @ 64x64, bf16 MFMA) -------
// W split into Wh+Wl (both bf16) for ~f32 accuracy; h is exactly bf16.
// Layouts (mfma_f32_16x16x32_bf16, verified C-map m89):
//   A[m][k]: m=lane&15, k=32s + (lane>>4)*8 + i
//   B[k][n]: n=lane&15, k=32s + (lane>>4)*8 + i
//   D[m][n]: n=lane&15, m=(lane>>4)*4 + j

__global__ __launch_bounds__(256) void k_gemm(
        const unsigned short* __restrict__ hin, const float* __restrict__ W,
        unsigned short* __restrict__ Y) {
    int lane = threadIdx.x & 63;
    int r = lane & 15;
    int g = lane >> 4;
    int wave   = blockIdx.x * (blockDim.x >> 6) + (threadIdx.x >> 6);
    int nwaves = gridDim.x * (blockDim.x >> 6);

    short8 bh[2][4], bl[2][4];
    #pragma unroll
    for (int s = 0; s < 2; ++s) {
        #pragma unroll
        for (int t = 0; t < 4; ++t) {
            short8 hv, lv;
            #pragma unroll
            for (int i = 0; i < 8; ++i) {
                int k = s * 32 + g * 8 + i;
                int n = t * 16 + r;
                float w = W[k * 64 + n];
                unsigned short wh = f2bf(w);
                float whf = bf2f(wh);
                hv[i] = (short)wh;
                lv[i] = (short)f2bf(w - whf);
            }
            bh[s][t] = hv; bl[s][t] = lv;
        }
    }

    const int NT = N_NODES / 16;   // 6250 (exact)
    for (int mt = wave; mt < NT; mt += nwaves) {
        const unsigned short* arow = hin + (size_t)(mt * 16 + r) * 64;
        short8 a0 = *(const short8*)(arow + g * 8);
        short8 a1 = *(const short8*)(arow + 32 + g * 8);
        #pragma unroll
        for (int t = 0; t < 4; ++t) {
            f32x4 acc = {0.f, 0.f, 0.f, 0.f};
            acc = __builtin_amdgcn_mfma_f32_16x16x32_bf16(a0, bh[0][t], acc, 0, 0, 0);
            acc = __builtin_amdgcn_mfma_f32_16x16x32_bf16(a0, bl[0][t], acc, 0, 0, 0);
            acc = __builtin_amdgcn_mfma_f32_16x16x32_bf16(a1, bh[1][t], acc, 0, 0, 0);
            acc = __builtin_amdgcn_mfma_f32_16x16x32_bf16(a1, bl[1][t], acc, 0, 0, 0);
            #pragma unroll
            for (int j = 0; j < 4; ++j) {
                sth(&Y[(size_t)(mt * 16 + g * 4 + j) * 64 + t * 16 + r], acc[j]);
            }
        }
    }
}

// ---------------- Gather: out = relu(b + (1+eps)*Y_self + sum_nbr Y_nbr) ------
// 16 lanes per node (4 nodes/wave). Lane sl holds feature quad 4sl..4sl+3.

__device__ inline void gather_node(
        const uint2* __restrict__ h2, const int* __restrict__ off,
        const int* __restrict__ adj, int node, int sl, int g4,
        float& a0, float& a1, float& a2, float& a3) {
    int o0 = off[node], o1 = off[node + 1];
    int deg = o1 - o0;
    int nchunk = (deg + 15) >> 4;
    for (int c = 0; c < nchunk; ++c) {
        int pos = o0 + (c << 4) + sl;
        int posc = pos < o1 ? pos : (o1 - 1);
        int idxv = adj[posc];
        int rem = deg - (c << 4);
        #pragma unroll
        for (int half = 0; half < 2; ++half) {
            uint2 dd[8];
            #pragma unroll
            for (int i = 0; i < 8; ++i) {
                int k = half * 8 + i;
                int s = __shfl(idxv, (g4 << 4) + k);
                dd[i] = h2[(size_t)s * 16 + sl];
            }
            #pragma unroll
            for (int i = 0; i < 8; ++i) {
                int k = half * 8 + i;
                int ok = k < rem;
                unsigned int lo = ok ? dd[i].x : 0u;
                unsigned int hc = ok ? dd[i].y : 0u;
                a0 += bflo(lo); a1 += bfhi(lo);
                a2 += bflo(hc); a3 += bfhi(hc);
            }
            if (rem <= 8) break;
        }
    }
}

__global__ __launch_bounds__(1024) void k_gather(
        const unsigned short* __restrict__ Y, const int* __restrict__ off,
        const int* __restrict__ adj, const float* __restrict__ epsp,
        const float* __restrict__ b, unsigned short* __restrict__ hout) {
    int tid  = blockIdx.x * 1024 + threadIdx.x;
    int node = tid >> 4;
    if (node >= N_NODES) return;
    int sl = threadIdx.x & 15;
    int g4 = (threadIdx.x >> 4) & 3;
    const uint2* h2 = (const uint2*)Y;
    float a0 = 0.f, a1 = 0.f, a2 = 0.f, a3 = 0.f;
    gather_node(h2, off, adj, node, sl, g4, a0, a1, a2, a3);
    uint2 ds = h2[(size_t)node * 16 + sl];
    float ep = 1.0f + epsp[0];
    a0 = fmaxf(a0 + ep * bflo(ds.x) + b[4 * sl + 0], 0.f);
    a1 = fmaxf(a1 + ep * bfhi(ds.x) + b[4 * sl + 1], 0.f);
    a2 = fmaxf(a2 + ep * bflo(ds.y) + b[4 * sl + 2], 0.f);
    a3 = fmaxf(a3 + ep * bfhi(ds.y) + b[4 * sl + 3], 0.f);
    uint2 o;
    o.x = (unsigned int)f2bf(a0) | ((unsigned int)f2bf(a1) << 16);
    o.y = (unsigned int)f2bf(a2) | ((unsigned int)f2bf(a3) << 16);
    ((uint2*)hout)[(size_t)node * 16 + sl] = o;
}

// layer-3 variant: pool directly (batch sorted); no feature store
__global__ __launch_bounds__(1024) void k_gather_pool(
        const unsigned short* __restrict__ Y, const int* __restrict__ off,
        const int* __restrict__ adj, const float* __restrict__ epsp,
        const float* __restrict__ b, const int* __restrict__ batch,
        float* __restrict__ pooled, int* __restrict__ cnt) {
    __shared__ float sacc[8 * 64];
    __shared__ int   scnt[8];
    for (int i = threadIdx.x; i < 8 * 64; i += 1024) sacc[i] = 0.f;
    if (threadIdx.x < 8) scnt[threadIdx.x] = 0;
    __syncthreads();

    int tid  = blockIdx.x * 1024 + threadIdx.x;
    int node = tid >> 4;
    int sl = threadIdx.x & 15;
    int g4 = (threadIdx.x >> 4) & 3;
    int g0 = clampi(batch[clampi(blockIdx.x << 6, 0, N_NODES - 1)], 0, N_GRAPHS - 1);

    if (node < N_NODES) {
        const uint2* h2 = (const uint2*)Y;
        float a0 = 0.f, a1 = 0.f, a2 = 0.f, a3 = 0.f;
        gather_node(h2, off, adj, node, sl, g4, a0, a1, a2, a3);
        uint2 ds = h2[(size_t)node * 16 + sl];
        float ep = 1.0f + epsp[0];
        a0 = fmaxf(a0 + ep * bflo(ds.x) + b[4 * sl + 0], 0.f);
        a1 = fmaxf(a1 + ep * bfhi(ds.x) + b[4 * sl + 1], 0.f);
        a2 = fmaxf(a2 + ep * bflo(ds.y) + b[4 * sl + 2], 0.f);
        a3 = fmaxf(a3 + ep * bfhi(ds.y) + b[4 * sl + 3], 0.f);
        int g  = clampi(batch[node], 0, N_GRAPHS - 1);
        int og = g - g0;
        if (og >= 0 && og < 8) {
            atomicAdd(&sacc[og * 64 + 4 * sl + 0], a0);
            atomicAdd(&sacc[og * 64 + 4 * sl + 1], a1);
            atomicAdd(&sacc[og * 64 + 4 * sl + 2], a2);
            atomicAdd(&sacc[og * 64 + 4 * sl + 3], a3);
            if (sl == 0) atomicAdd(&scnt[og], 1);
        } else {
            atomicAdd(&pooled[g * 64 + 4 * sl + 0], a0);
            atomicAdd(&pooled[g * 64 + 4 * sl + 1], a1);
            atomicAdd(&pooled[g * 64 + 4 * sl + 2], a2);
            atomicAdd(&pooled[g * 64 + 4 * sl + 3], a3);
            if (sl == 0) atomicAdd(&cnt[g], 1);
        }
    }
    __syncthreads();
    int w = threadIdx.x >> 6;                // waves 0..7 flush slots
    int lane = threadIdx.x & 63;
    if (w < 8) {
        int c = scnt[w];
        if (c > 0) {
            atomicAdd(&pooled[(g0 + w) * 64 + lane], sacc[w * 64 + lane]);
            if (lane == 0) atomicAdd(&cnt[g0 + w], c);
        }
    }
}

// ---------------- Head: mean, 64->10 relu, 10->1 ----------------

__global__ __launch_bounds__(256) void k_head(
        const float* __restrict__ pooled, const int* __restrict__ cnt,
        const float* __restrict__ Wf1, const float* __restrict__ bf1,
        const float* __restrict__ Wf2, const float* __restrict__ bf2,
        float* __restrict__ out) {
    int g = blockIdx.x * blockDim.x + threadIdx.x;
    if (g >= N_GRAPHS) return;
    float inv = 1.0f / fmaxf((float)cnt[g], 1.0f);
    float p[64];
    #pragma unroll
    for (int k = 0; k < 64; ++k) p[k] = pooled[g * 64 + k] * inv;
    float o = bf2[0];
    #pragma unroll
    for (int j = 0; j < 10; ++j) {
        float s = bf1[j];
        #pragma unroll
        for (int k = 0; k < 64; ++k) s += p[k] * Wf1[k * 10 + j];
        o += fmaxf(s, 0.f) * Wf2[j];
    }
    out[g] = o;
}

// ---------------- launch ----------------

extern "C" void kernel_launch(void* const* d_in, const int* in_sizes, int n_in,
                              void* d_out, int out_size, void* d_ws, size_t ws_size,
                              hipStream_t stream) {
    const float* x     = (const float*)d_in[0];
    const int*   ei    = (const int*)d_in[1];    // int64 in ref -> int32 on device
    const int*   batch = (const int*)d_in[2];
    const float* eps1 = (const float*)d_in[3];
    const float* eps2 = (const float*)d_in[4];
    const float* eps3 = (const float*)d_in[5];
    const float* W1 = (const float*)d_in[6];
    const float* b1 = (const float*)d_in[7];
    const float* W2 = (const float*)d_in[8];
    const float* b2 = (const float*)d_in[9];
    const float* W3 = (const float*)d_in[10];
    const float* b3 = (const float*)d_in[11];
    const float* Wf1 = (const float*)d_in[12];
    const float* bf1 = (const float*)d_in[13];
    const float* Wf2 = (const float*)d_in[14];
    const float* bf2 = (const float*)d_in[15];
    float* out = (float*)d_out;

    const size_t H64 = (size_t)N_NODES * HDIM;          // 6,400,000 elems

    char* base = (char*)d_ws;
    unsigned short* hA = (unsigned short*)base;                    // 12.8 MB
    unsigned short* hB = (unsigned short*)(base + H64 * 2);        // 12.8 MB
    char* q = base + 2 * H64 * 2;
    float* pooled = (float*)q;            q += 64000ull * 4;
    int*   cnt    = (int*)q;              q += 1000ull * 4;
    int*   deg    = (int*)q;              q += 100000ull * 4;
    int*   off    = (int*)q;              q += 100004ull * 4;
    int*   bsum   = (int*)q;              q += 128ull * 4;
    int*   adj    = (int*)q;

    const int TB = 256;
    k_zero<<<(N_NODES + TB - 1) / TB, TB, 0, stream>>>(deg, N_NODES);
    k_zero<<<(65000 + TB - 1) / TB, TB, 0, stream>>>((int*)pooled, 65000);

    // CSR build
    k_count<<<(N_EDGES + TB - 1) / TB, TB, 0, stream>>>(ei, deg);
    k_scan1<<<NBLK, SCAN_B, 0, stream>>>(deg, off, bsum);
    k_scan2<<<1, 128, 0, stream>>>(bsum);
    k_scan3<<<NBLK, SCAN_B, 0, stream>>>(off, deg, bsum);   // deg becomes cursor
    dim3 egrid((N_EDGES + TB - 1) / TB, NPASS);
    k_fill<<<egrid, TB, 0, stream>>>(ei, deg, adj);

    const int L1_BLOCKS = (int)((H64 + TB - 1) / TB);        // 4 nodes/block @256
    const int GB = (N_NODES * 16 + 1023) / 1024;             // gather blocks (64 nodes ea)

    // layer 1 (fused, cheap gathers of 12B x-rows)
    k_layer1<<<L1_BLOCKS, TB, 0, stream>>>(x, off, adj, eps1, W1, b1, hA);
    // layer 2: GEMM then gather
    k_gemm<<<256, 256, 0, stream>>>(hA, W2, hB);
    k_gather<<<GB, 1024, 0, stream>>>(hB, off, adj, eps2, b2, hA);
    // layer 3: GEMM then gather+pool
    k_gemm<<<256, 256, 0, stream>>>(hA, W3, hB);
    k_gather_pool<<<GB, 1024, 0, stream>>>(hB, off, adj, eps3, b3, batch, pooled, cnt);

    k_head<<<(N_GRAPHS + TB - 1) / TB, TB, 0, stream>>>(pooled, cnt, Wf1, bf1, Wf2, bf2, out);
}

// Round 9
// 465.985 us; speedup vs baseline: 2.9055x; 1.0381x over previous
//
#include <hip/hip_runtime.h>

#define N_NODES  100000
#define N_EDGES  3200000
#define N_GRAPHS 1000
#define HDIM     64

#define NWIN     8                                  // one dst-window per XCD
#define WIN_SZ   ((N_NODES + NWIN - 1) / NWIN)      // 12500
#define SCAN_B   1024
#define NBLK     ((N_NODES + SCAN_B - 1) / SCAN_B)  // 98

typedef __attribute__((ext_vector_type(8))) short short8;
typedef __attribute__((ext_vector_type(4))) float f32x4;

// ---------------- bf16 (storage) <-> f32 (math) ----------------

__device__ inline unsigned short f2bf(float v) {
    unsigned int b; __builtin_memcpy(&b, &v, 4);
    return (unsigned short)((b + 0x7FFFu + ((b >> 16) & 1u)) >> 16);   // RNE
}
__device__ inline float bf2f(unsigned short u) {
    return __uint_as_float(((unsigned int)u) << 16);
}
__device__ inline void sth(unsigned short* p, float v) { *p = f2bf(v); }
__device__ inline float bflo(unsigned int d) { return __uint_as_float(d << 16); }
__device__ inline float bfhi(unsigned int d) { return __uint_as_float(d & 0xFFFF0000u); }

__device__ inline int clampi(int v, int lo, int hi) {
    return v < lo ? lo : (v > hi ? hi : v);
}

// ---------------- utility ----------------

__global__ void k_zero(int* __restrict__ p, int n) {
    int i = blockIdx.x * blockDim.x + threadIdx.x;
    if (i < n) p[i] = 0;
}

// ---------------- CSR construction ----------------

__global__ void k_count(const int* __restrict__ ei, int* __restrict__ deg) {
    int e = blockIdx.x * blockDim.x + threadIdx.x;
    if (e < N_EDGES) {
        int d = clampi(ei[N_EDGES + e], 0, N_NODES - 1);
        atomicAdd(&deg[d], 1);
    }
}

__global__ __launch_bounds__(SCAN_B) void k_scan1(
        const int* __restrict__ deg, int* __restrict__ off, int* __restrict__ bsum) {
    __shared__ int s[SCAN_B];
    int t = threadIdx.x;
    int i = blockIdx.x * SCAN_B + t;
    int v = (i < N_NODES) ? deg[i] : 0;
    s[t] = v;
    __syncthreads();
    #pragma unroll
    for (int d = 1; d < SCAN_B; d <<= 1) {
        int add = (t >= d) ? s[t - d] : 0;
        __syncthreads();
        s[t] += add;
        __syncthreads();
    }
    if (i < N_NODES) off[i] = s[t] - v;          // exclusive within block
    if (t == SCAN_B - 1) bsum[blockIdx.x] = s[t];
}

__global__ void k_scan2(int* __restrict__ bsum) {
    __shared__ int s[NBLK + 1];
    int t = threadIdx.x;
    if (t < NBLK) s[t] = bsum[t];
    __syncthreads();
    if (t == 0) {
        int run = 0;
        for (int i = 0; i < NBLK; ++i) { int x = s[i]; s[i] = run; run += x; }
        s[NBLK] = run;
    }
    __syncthreads();
    if (t <= NBLK) bsum[t] = s[t];
}

__global__ __launch_bounds__(SCAN_B) void k_scan3(
        int* __restrict__ off, int* __restrict__ cur, const int* __restrict__ bsum) {
    int i = blockIdx.x * SCAN_B + threadIdx.x;
    if (i < N_NODES) {
        int v = off[i] + bsum[blockIdx.x];
        off[i] = v;
        cur[i] = v;
    }
    if (i == 0) off[N_NODES] = bsum[NBLK];       // total
}

// XCD-aligned windowed fill: window w is processed only by blocks with
// linear blockIdx % 8 == w, which round-robin onto XCD w -> that XCD's L2
// exclusively owns the window's adj slice and evicts full lines once.
__global__ __launch_bounds__(256) void k_fill(
        const int* __restrict__ ei, int* __restrict__ cur, int* __restrict__ adj) {
    int win   = blockIdx.x & (NWIN - 1);
    int chunk = blockIdx.x >> 3;
    int lo = win * WIN_SZ;
    int hi = lo + WIN_SZ;
    int e0 = (chunk * 256 + threadIdx.x) * 4;
    if (e0 >= N_EDGES) return;
    const int4* dst4 = (const int4*)(ei + N_EDGES);
    int4 d4 = dst4[e0 >> 2];
    #pragma unroll
    for (int i = 0; i < 4; ++i) {
        int d = (i == 0) ? d4.x : (i == 1) ? d4.y : (i == 2) ? d4.z : d4.w;
        d = clampi(d, 0, N_NODES - 1);
        if (d >= lo && d < hi) {
            int s = clampi(ei[e0 + i], 0, N_NODES - 1);
            int q = atomicAdd(&cur[d], 1);
            if (q >= 0 && q < N_EDGES) adj[q] = s;
        }
    }
}

// ---------------- Layer 1 (F_IN = 3): fused agg + 3x64 matmul ----------------

__global__ __launch_bounds__(256) void k_layer1(
        const float* __restrict__ x, const int* __restrict__ off,
        const int* __restrict__ adj, const float* __restrict__ epsp,
        const float* __restrict__ W1, const float* __restrict__ b1,
        unsigned short* __restrict__ hout) {
    int wid  = (blockIdx.x * blockDim.x + threadIdx.x) >> 6;   // node
    int lane = threadIdx.x & 63;
    if (wid >= N_NODES) return;
    int o0 = off[wid], o1 = off[wid + 1];
    float a0 = 0.f, a1 = 0.f, a2 = 0.f;
    for (int e = o0 + lane; e < o1; e += 64) {
        int s = adj[e];
        a0 += x[s * 3 + 0];
        a1 += x[s * 3 + 1];
        a2 += x[s * 3 + 2];
    }
    #pragma unroll
    for (int d = 32; d; d >>= 1) {
        a0 += __shfl_xor(a0, d);
        a1 += __shfl_xor(a1, d);
        a2 += __shfl_xor(a2, d);
    }
    float ep = 1.0f + epsp[0];
    float s0 = ep * x[wid * 3 + 0] + a0;
    float s1 = ep * x[wid * 3 + 1] + a1;
    float s2 = ep * x[wid * 3 + 2] + a2;
    float o = b1[lane] + s0 * W1[lane] + s1 * W1[64 + lane] + s2 * W1[128 + lane];
    sth(&hout[(size_t)wid * 64 + lane], fmaxf(o, 0.f));
}

// ---------------- Dense GEMM: Y = h @ W  (100000x64 @ 64x64, bf16 MFMA) -------
// W split into Wh+Wl (both bf16) for ~f32 accuracy; h is exactly bf16.
// Layouts (mfma_f32_16x16x32_bf16, verified C-map m89):
//   A[m][k]: m=lane&15, k=32s + (lane>>4)*8 + i
//   B[k][n]: n=lane&15, k=32s + (lane>>4)*8 + i
//   D[m][n]: n=lane&15, m=(lane>>4)*4 + j

__global__ __launch_bounds__(256) void k_gemm(
        const unsigned short* __restrict__ hin, const float* __restrict__ W,
        unsigned short* __restrict__ Y) {
    int lane = threadIdx.x & 63;
    int r = lane & 15;
    int g = lane >> 4;
    int wave   = blockIdx.x * (blockDim.x >> 6) + (threadIdx.x >> 6);
    int nwaves = gridDim.x * (blockDim.x >> 6);

    short8 bh[2][4], bl[2][4];
    #pragma unroll
    for (int s = 0; s < 2; ++s) {
        #pragma unroll
        for (int t = 0; t < 4; ++t) {
            short8 hv, lv;
            #pragma unroll
            for (int i = 0; i < 8; ++i) {
                int k = s * 32 + g * 8 + i;
                int n = t * 16 + r;
                float w = W[k * 64 + n];
                unsigned short wh = f2bf(w);
                float whf = bf2f(wh);
                hv[i] = (short)wh;
                lv[i] = (short)f2bf(w - whf);
            }
            bh[s][t] = hv; bl[s][t] = lv;
        }
    }

    const int NT = N_NODES / 16;   // 6250 (exact)
    for (int mt = wave; mt < NT; mt += nwaves) {
        const unsigned short* arow = hin + (size_t)(mt * 16 + r) * 64;
        short8 a0 = *(const short8*)(arow + g * 8);
        short8 a1 = *(const short8*)(arow + 32 + g * 8);
        #pragma unroll
        for (int t = 0; t < 4; ++t) {
            f32x4 acc = {0.f, 0.f, 0.f, 0.f};
            acc = __builtin_amdgcn_mfma_f32_16x16x32_bf16(a0, bh[0][t], acc, 0, 0, 0);
            acc = __builtin_amdgcn_mfma_f32_16x16x32_bf16(a0, bl[0][t], acc, 0, 0, 0);
            acc = __builtin_amdgcn_mfma_f32_16x16x32_bf16(a1, bh[1][t], acc, 0, 0, 0);
            acc = __builtin_amdgcn_mfma_f32_16x16x32_bf16(a1, bl[1][t], acc, 0, 0, 0);
            #pragma unroll
            for (int j = 0; j < 4; ++j) {
                sth(&Y[(size_t)(mt * 16 + g * 4 + j) * 64 + t * 16 + r], acc[j]);
            }
        }
    }
}

// ---------------- Gather: out = relu(b + (1+eps)*Y_self + sum_nbr Y_nbr) ------
// 16 lanes per node (4 nodes/wave). Lane sl holds feature quad 4sl..4sl+3.

__device__ inline void gather_node(
        const uint2* __restrict__ h2, const int* __restrict__ off,
        const int* __restrict__ adj, int node, int sl, int g4,
        float& a0, float& a1, float& a2, float& a3) {
    int o0 = off[node], o1 = off[node + 1];
    int deg = o1 - o0;
    int nchunk = (deg + 15) >> 4;
    for (int c = 0; c < nchunk; ++c) {
        int pos = o0 + (c << 4) + sl;
        int posc = pos < o1 ? pos : (o1 - 1);
        int idxv = adj[posc];
        int rem = deg - (c << 4);
        #pragma unroll
        for (int half = 0; half < 2; ++half) {
            uint2 dd[8];
            #pragma unroll
            for (int i = 0; i < 8; ++i) {
                int k = half * 8 + i;
                int s = __shfl(idxv, (g4 << 4) + k);
                dd[i] = h2[(size_t)s * 16 + sl];
            }
            #pragma unroll
            for (int i = 0; i < 8; ++i) {
                int k = half * 8 + i;
                int ok = k < rem;
                unsigned int lo = ok ? dd[i].x : 0u;
                unsigned int hc = ok ? dd[i].y : 0u;
                a0 += bflo(lo); a1 += bfhi(lo);
                a2 += bflo(hc); a3 += bfhi(hc);
            }
            if (rem <= 8) break;
        }
    }
}

__global__ __launch_bounds__(1024) void k_gather(
        const unsigned short* __restrict__ Y, const int* __restrict__ off,
        const int* __restrict__ adj, const float* __restrict__ epsp,
        const float* __restrict__ b, unsigned short* __restrict__ hout) {
    int tid  = blockIdx.x * 1024 + threadIdx.x;
    int node = tid >> 4;
    if (node >= N_NODES) return;
    int sl = threadIdx.x & 15;
    int g4 = (threadIdx.x >> 4) & 3;
    const uint2* h2 = (const uint2*)Y;
    float a0 = 0.f, a1 = 0.f, a2 = 0.f, a3 = 0.f;
    gather_node(h2, off, adj, node, sl, g4, a0, a1, a2, a3);
    uint2 ds = h2[(size_t)node * 16 + sl];
    float ep = 1.0f + epsp[0];
    a0 = fmaxf(a0 + ep * bflo(ds.x) + b[4 * sl + 0], 0.f);
    a1 = fmaxf(a1 + ep * bfhi(ds.x) + b[4 * sl + 1], 0.f);
    a2 = fmaxf(a2 + ep * bflo(ds.y) + b[4 * sl + 2], 0.f);
    a3 = fmaxf(a3 + ep * bfhi(ds.y) + b[4 * sl + 3], 0.f);
    uint2 o;
    o.x = (unsigned int)f2bf(a0) | ((unsigned int)f2bf(a1) << 16);
    o.y = (unsigned int)f2bf(a2) | ((unsigned int)f2bf(a3) << 16);
    ((uint2*)hout)[(size_t)node * 16 + sl] = o;
}

// layer-3 variant: pool directly (batch sorted); no feature store
__global__ __launch_bounds__(1024) void k_gather_pool(
        const unsigned short* __restrict__ Y, const int* __restrict__ off,
        const int* __restrict__ adj, const float* __restrict__ epsp,
        const float* __restrict__ b, const int* __restrict__ batch,
        float* __restrict__ pooled, int* __restrict__ cnt) {
    __shared__ float sacc[8 * 64];
    __shared__ int   scnt[8];
    for (int i = threadIdx.x; i < 8 * 64; i += 1024) sacc[i] = 0.f;
    if (threadIdx.x < 8) scnt[threadIdx.x] = 0;
    __syncthreads();

    int tid  = blockIdx.x * 1024 + threadIdx.x;
    int node = tid >> 4;
    int sl = threadIdx.x & 15;
    int g4 = (threadIdx.x >> 4) & 3;
    int g0 = clampi(batch[clampi(blockIdx.x << 6, 0, N_NODES - 1)], 0, N_GRAPHS - 1);

    if (node < N_NODES) {
        const uint2* h2 = (const uint2*)Y;
        float a0 = 0.f, a1 = 0.f, a2 = 0.f, a3 = 0.f;
        gather_node(h2, off, adj, node, sl, g4, a0, a1, a2, a3);
        uint2 ds = h2[(size_t)node * 16 + sl];
        float ep = 1.0f + epsp[0];
        a0 = fmaxf(a0 + ep * bflo(ds.x) + b[4 * sl + 0], 0.f);
        a1 = fmaxf(a1 + ep * bfhi(ds.x) + b[4 * sl + 1], 0.f);
        a2 = fmaxf(a2 + ep * bflo(ds.y) + b[4 * sl + 2], 0.f);
        a3 = fmaxf(a3 + ep * bfhi(ds.y) + b[4 * sl + 3], 0.f);
        int g  = clampi(batch[node], 0, N_GRAPHS - 1);
        int og = g - g0;
        if (og >= 0 && og < 8) {
            atomicAdd(&sacc[og * 64 + 4 * sl + 0], a0);
            atomicAdd(&sacc[og * 64 + 4 * sl + 1], a1);
            atomicAdd(&sacc[og * 64 + 4 * sl + 2], a2);
            atomicAdd(&sacc[og * 64 + 4 * sl + 3], a3);
            if (sl == 0) atomicAdd(&scnt[og], 1);
        } else {
            atomicAdd(&pooled[g * 64 + 4 * sl + 0], a0);
            atomicAdd(&pooled[g * 64 + 4 * sl + 1], a1);
            atomicAdd(&pooled[g * 64 + 4 * sl + 2], a2);
            atomicAdd(&pooled[g * 64 + 4 * sl + 3], a3);
            if (sl == 0) atomicAdd(&cnt[g], 1);
        }
    }
    __syncthreads();
    int w = threadIdx.x >> 6;                // waves 0..7 flush slots
    int lane = threadIdx.x & 63;
    if (w < 8) {
        int c = scnt[w];
        if (c > 0) {
            atomicAdd(&pooled[(g0 + w) * 64 + lane], sacc[w * 64 + lane]);
            if (lane == 0) atomicAdd(&cnt[g0 + w], c);
        }
    }
}

// ---------------- Head: mean, 64->10 relu, 10->1 ----------------

__global__ __launch_bounds__(256) void k_head(
        const float* __restrict__ pooled, const int* __restrict__ cnt,
        const float* __restrict__ Wf1, const float* __restrict__ bf1,
        const float* __restrict__ Wf2, const float* __restrict__ bf2,
        float* __restrict__ out) {
    int g = blockIdx.x * blockDim.x + threadIdx.x;
    if (g >= N_GRAPHS) return;
    float inv = 1.0f / fmaxf((float)cnt[g], 1.0f);
    float p[64];
    #pragma unroll
    for (int k = 0; k < 64; ++k) p[k] = pooled[g * 64 + k] * inv;
    float o = bf2[0];
    #pragma unroll
    for (int j = 0; j < 10; ++j) {
        float s = bf1[j];
        #pragma unroll
        for (int k = 0; k < 64; ++k) s += p[k] * Wf1[k * 10 + j];
        o += fmaxf(s, 0.f) * Wf2[j];
    }
    out[g] = o;
}

// ---------------- launch ----------------

extern "C" void kernel_launch(void* const* d_in, const int* in_sizes, int n_in,
                              void* d_out, int out_size, void* d_ws, size_t ws_size,
                              hipStream_t stream) {
    const float* x     = (const float*)d_in[0];
    const int*   ei    = (const int*)d_in[1];    // int64 in ref -> int32 on device
    const int*   batch = (const int*)d_in[2];
    const float* eps1 = (const float*)d_in[3];
    const float* eps2 = (const float*)d_in[4];
    const float* eps3 = (const float*)d_in[5];
    const float* W1 = (const float*)d_in[6];
    const float* b1 = (const float*)d_in[7];
    const float* W2 = (const float*)d_in[8];
    const float* b2 = (const float*)d_in[9];
    const float* W3 = (const float*)d_in[10];
    const float* b3 = (const float*)d_in[11];
    const float* Wf1 = (const float*)d_in[12];
    const float* bf1 = (const float*)d_in[13];
    const float* Wf2 = (const float*)d_in[14];
    const float* bf2 = (const float*)d_in[15];
    float* out = (float*)d_out;

    const size_t H64 = (size_t)N_NODES * HDIM;          // 6,400,000 elems

    char* base = (char*)d_ws;
    unsigned short* hA = (unsigned short*)base;                    // 12.8 MB
    unsigned short* hB = (unsigned short*)(base + H64 * 2);        // 12.8 MB
    char* q = base + 2 * H64 * 2;
    float* pooled = (float*)q;            q += 64000ull * 4;
    int*   cnt    = (int*)q;              q += 1000ull * 4;
    int*   deg    = (int*)q;              q += 100000ull * 4;
    int*   off    = (int*)q;              q += 100004ull * 4;
    int*   bsum   = (int*)q;              q += 128ull * 4;
    int*   adj    = (int*)q;

    const int TB = 256;
    k_zero<<<(N_NODES + TB - 1) / TB, TB, 0, stream>>>(deg, N_NODES);
    k_zero<<<(65000 + TB - 1) / TB, TB, 0, stream>>>((int*)pooled, 65000);

    // CSR build
    k_count<<<(N_EDGES + TB - 1) / TB, TB, 0, stream>>>(ei, deg);
    k_scan1<<<NBLK, SCAN_B, 0, stream>>>(deg, off, bsum);
    k_scan2<<<1, 128, 0, stream>>>(bsum);
    k_scan3<<<NBLK, SCAN_B, 0, stream>>>(off, deg, bsum);   // deg becomes cursor
    // XCD-aligned windowed fill: 4 edges/thread, 8 windows interleaved on blockIdx
    const int FCHUNKS = (N_EDGES + TB * 4 - 1) / (TB * 4);   // 3125
    k_fill<<<FCHUNKS * NWIN, TB, 0, stream>>>(ei, deg, adj);

    const int L1_BLOCKS = (int)((H64 + TB - 1) / TB);        // 4 nodes/block @256
    const int GB = (N_NODES * 16 + 1023) / 1024;             // gather blocks (64 nodes ea)

    // layer 1 (fused, cheap gathers of 12B x-rows)
    k_layer1<<<L1_BLOCKS, TB, 0, stream>>>(x, off, adj, eps1, W1, b1, hA);
    // layer 2: GEMM then gather
    k_gemm<<<256, 256, 0, stream>>>(hA, W2, hB);
    k_gather<<<GB, 1024, 0, stream>>>(hB, off, adj, eps2, b2, hA);
    // layer 3: GEMM then gather+pool
    k_gemm<<<256, 256, 0, stream>>>(hA, W3, hB);
    k_gather_pool<<<GB, 1024, 0, stream>>>(hB, off, adj, eps3, b3, batch, pooled, cnt);

    k_head<<<(N_GRAPHS + TB - 1) / TB, TB, 0, stream>>>(pooled, cnt, Wf1, bf1, Wf2, bf2, out);
}